// Round 1
// baseline (2044.498 us; speedup 1.0000x reference)
//
#include <hip/hip_runtime.h>

#define DIM 64
#define MTILE 128        // rows per block
#define THREADS 256
#define T_LEN 2048
#define WPITCH 68        // fp32 anorm staging window pitch (overlaid on pool)
#define THR 2e-3f        // capture margin (proven pairwise bound 1.53e-3)
#define CAP 6            // per-(lane,row-tile) candidate list capacity
#define RT_N 8           // row-tiles (16 rows each) per block

typedef __attribute__((ext_vector_type(8))) short short8;
typedef __attribute__((ext_vector_type(4))) float f32x4;

// monotone order-preserving map float -> u32
__device__ __forceinline__ unsigned int fmap32(float s) {
    unsigned int b = __float_as_uint(s);
    return (b & 0x80000000u) ? ~b : (b | 0x80000000u);
}
__device__ __forceinline__ float funmap32(unsigned int m) {
    unsigned int b = (m & 0x80000000u) ? (m & 0x7fffffffu) : ~m;
    return __uint_as_float(b);
}
// fp32 -> bf16 RTNE
__device__ __forceinline__ unsigned int f2bf(float f) {
    unsigned int u = __float_as_uint(f);
    return (u + 0x7FFFu + ((u >> 16) & 1u)) >> 16;
}
// numpy pairwise-sum (n=64 scalar blocked path) combine tree over 8 partials
__device__ __forceinline__ float np_combine8(const float* r) {
    return __fadd_rn(__fadd_rn(__fadd_rn(r[0], r[1]), __fadd_rn(r[2], r[3])),
                     __fadd_rn(__fadd_rn(r[4], r[5]), __fadd_rn(r[6], r[7])));
}
// numpy-bit-exact distance key for one (row, code) pair (verified r2-r6)
__device__ __forceinline__ unsigned long long np_key(
        const float* __restrict__ xr, const float* __restrict__ cr,
        float an, float bn, int k) {
    float acc = 0.0f;
    #pragma unroll
    for (int i = 0; i < DIM; ++i) acc = __fmaf_rn(xr[i], cr[i], acc);
    float t1 = __fadd_rn(an, bn);
    float d  = __fsub_rn(t1, __fmul_rn(2.0f, acc));
    return ((unsigned long long)fmap32(d) << 12) | (unsigned long long)k;
}

__global__ void vq_init_ws(double* ws) { ws[0] = 0.0; }

__global__ void vq_finalize_atomic(const double* __restrict__ ws,
                                   float* __restrict__ out_loss, int n_el) {
    out_loss[0] = (float)(1.25 * ws[0] / (double)n_el);
}

__global__ void vq_finalize_part(const double* __restrict__ ws,
                                 float* __restrict__ out_loss, int n_el) {
    __shared__ double red[8];
    double v = ws[threadIdx.x];
    #pragma unroll
    for (int off = 32; off > 0; off >>= 1) v += __shfl_down(v, off, 64);
    if ((threadIdx.x & 63) == 0) red[threadIdx.x >> 6] = v;
    __syncthreads();
    if (threadIdx.x == 0) {
        double s = 0.0;
        #pragma unroll
        for (int i = 0; i < 8; ++i) s += red[i];
        out_loss[0] = (float)(1.25 * s / (double)n_el);
    }
}

// Swapped-operand MFMA (codes as A-operand): lane col = row, regs = codes.
// Min-sweep + running-lim candidate capture fully in registers — no dmat,
// no main-loop barriers. Per-(lane,rt) single-writer lists, superset-safe
// (lane-local runmin >= global runmin). np-bit-exact refine unchanged;
// overflowed rows fall back to wave-parallel exhaustive np scan.
__global__ __launch_bounds__(THREADS) void vq_main(
        const float* __restrict__ x,
        const float* __restrict__ cb,
        float* __restrict__ out_q,
        float* __restrict__ out_idx,
        double* __restrict__ wsd,
        int use_partials)
{
    // pool: candidate lists (256*8*6*2B = 24576B), overlaid with the fp32
    // anorm staging window (64*68*4B = 17408B) used only in the prologue.
    __shared__ alignas(16) char pool[THREADS * RT_N * CAP * 2];
    __shared__ float  bnorm[1024];
    __shared__ float  anorm[MTILE];
    __shared__ int    kstar[MTILE];
    __shared__ double lossd[MTILE];
    __shared__ unsigned long long wkey[4][MTILE];
    __shared__ int    wovf[4][MTILE];
    __shared__ int    ovfrows[MTILE];
    __shared__ int    ovfcnt;

    const int tid  = threadIdx.x;
    const int lane = tid & 63;
    const int wv   = tid >> 6;         // wave 0..3
    const int col  = lane & 15;
    const int quad = lane >> 4;        // 0..3
    const int r0   = blockIdx.x * MTILE;

    if (tid == 0) ovfcnt = 0;

    // ---- B_k for all 1024 codes (numpy register routine, verified r2-r6) ----
    #pragma unroll
    for (int j = 0; j < 4; ++j) {
        int k = tid * 4 + j;
        const float4* c4 = (const float4*)(cb + (size_t)k * DIM);
        float r8[8];
        {
            float4 a = c4[0], b = c4[1];
            r8[0] = __fmul_rn(a.x, a.x); r8[1] = __fmul_rn(a.y, a.y);
            r8[2] = __fmul_rn(a.z, a.z); r8[3] = __fmul_rn(a.w, a.w);
            r8[4] = __fmul_rn(b.x, b.x); r8[5] = __fmul_rn(b.y, b.y);
            r8[6] = __fmul_rn(b.z, b.z); r8[7] = __fmul_rn(b.w, b.w);
        }
        #pragma unroll
        for (int m = 1; m < 8; ++m) {
            float4 a = c4[2 * m], b = c4[2 * m + 1];
            r8[0] = __fadd_rn(r8[0], __fmul_rn(a.x, a.x));
            r8[1] = __fadd_rn(r8[1], __fmul_rn(a.y, a.y));
            r8[2] = __fadd_rn(r8[2], __fmul_rn(a.z, a.z));
            r8[3] = __fadd_rn(r8[3], __fmul_rn(a.w, a.w));
            r8[4] = __fadd_rn(r8[4], __fmul_rn(b.x, b.x));
            r8[5] = __fadd_rn(r8[5], __fmul_rn(b.y, b.y));
            r8[6] = __fadd_rn(r8[6], __fmul_rn(b.z, b.z));
            r8[7] = __fadd_rn(r8[7], __fmul_rn(b.w, b.w));
        }
        bnorm[k] = np_combine8(r8);
    }

    // ---- A_n for 128 rows via fp32 window overlaid on pool (verified r2-r6) ----
    float* CSW = (float*)pool;
    const float4* x4 = (const float4*)x;
    for (int sb = 0; sb < 2; ++sb) {
        #pragma unroll
        for (int it = 0; it < 4; ++it) {
            int idx = it * THREADS + tid;
            int row = idx >> 4, f4 = idx & 15;
            float4 v = x4[(size_t)(r0 + sb * 64 + row) * 16 + f4];
            *(float4*)&CSW[row * WPITCH + f4 * 4] = v;
        }
        __syncthreads();
        for (int j = 0; j < 16; ++j) {
            int rl = wv * 16 + j;
            float v  = CSW[rl * WPITCH + lane];
            float pp = __fmul_rn(v, v);
            float r = __fadd_rn(pp, __shfl_down(pp, 8, 64));
            r = __fadd_rn(r, __shfl_down(pp, 16, 64));
            r = __fadd_rn(r, __shfl_down(pp, 24, 64));
            r = __fadd_rn(r, __shfl_down(pp, 32, 64));
            r = __fadd_rn(r, __shfl_down(pp, 40, 64));
            r = __fadd_rn(r, __shfl_down(pp, 48, 64));
            r = __fadd_rn(r, __shfl_down(pp, 56, 64));
            float rr[8];
            #pragma unroll
            for (int q = 0; q < 8; ++q) rr[q] = __shfl(r, q, 64);
            if (lane == 0) anorm[sb * 64 + rl] = np_combine8(rr);
        }
        __syncthreads();
    }

    // ---- A (row) fragments direct from global with in-lane bf16 convert ----
    // Layout: col = row-within-tile, quad*8+e (+kh*32) = k. Valid as either
    // MFMA operand (A/B lane layouts are symmetric for 16x16x32).
    short8 afr[RT_N][2];
    #pragma unroll
    for (int mt = 0; mt < RT_N; ++mt) {
        #pragma unroll
        for (int kh = 0; kh < 2; ++kh) {
            const float* ap = x + (size_t)(r0 + mt * 16 + col) * DIM + kh * 32 + quad * 8;
            float4 a = *(const float4*)ap;
            float4 b = *(const float4*)(ap + 4);
            short8 s;
            s[0] = (short)f2bf(a.x); s[1] = (short)f2bf(a.y);
            s[2] = (short)f2bf(a.z); s[3] = (short)f2bf(a.w);
            s[4] = (short)f2bf(b.x); s[5] = (short)f2bf(b.y);
            s[6] = (short)f2bf(b.z); s[7] = (short)f2bf(b.w);
            afr[mt][kh] = s;
        }
    }

    unsigned short* myl = (unsigned short*)pool + (size_t)tid * (RT_N * CAP);
    float runmin[RT_N];
    int   cnt[RT_N];
    #pragma unroll
    for (int rt = 0; rt < RT_N; ++rt) { runmin[rt] = 3.4e38f; cnt[rt] = 0; }

    // ---- main loop: this wave handles code-tiles kt = 4*t + wv (16 tiles) ----
    // Codes as FIRST mfma operand -> output regs index codes, col indexes row.
    // Code loads register-double-buffered; no barriers in this loop.
    const float* bp0 = cb + (size_t)(wv * 16 + col) * DIM + quad * 8;
    float4 pa = *(const float4*)(bp0);
    float4 pb = *(const float4*)(bp0 + 4);
    float4 pc = *(const float4*)(bp0 + 32);
    float4 pd = *(const float4*)(bp0 + 36);

    #pragma unroll 1
    for (int t = 0; t < 16; ++t) {
        const int kbase = (t * 4 + wv) * 16;
        float4 ca = pa, cb4 = pb, cc = pc, cd = pd;
        if (t < 15) {
            const float* nxt = bp0 + (size_t)(t + 1) * 4096;  // 4 tiles * 16 codes * 64
            pa = *(const float4*)(nxt);
            pb = *(const float4*)(nxt + 4);
            pc = *(const float4*)(nxt + 32);
            pd = *(const float4*)(nxt + 36);
        }
        short8 b0, b1;
        b0[0] = (short)f2bf(ca.x);  b0[1] = (short)f2bf(ca.y);
        b0[2] = (short)f2bf(ca.z);  b0[3] = (short)f2bf(ca.w);
        b0[4] = (short)f2bf(cb4.x); b0[5] = (short)f2bf(cb4.y);
        b0[6] = (short)f2bf(cb4.z); b0[7] = (short)f2bf(cb4.w);
        b1[0] = (short)f2bf(cc.x);  b1[1] = (short)f2bf(cc.y);
        b1[2] = (short)f2bf(cc.z);  b1[3] = (short)f2bf(cc.w);
        b1[4] = (short)f2bf(cd.x);  b1[5] = (short)f2bf(cd.y);
        b1[6] = (short)f2bf(cd.z);  b1[7] = (short)f2bf(cd.w);
        const f32x4 bn4 = *(const f32x4*)&bnorm[kbase + quad * 4];
        const int kb = kbase + quad * 4;

        #pragma unroll
        for (int rt = 0; rt < RT_N; ++rt) {
            f32x4 acc = {0.f, 0.f, 0.f, 0.f};
            acc = __builtin_amdgcn_mfma_f32_16x16x32_bf16(b0, afr[rt][0], acc, 0, 0, 0);
            acc = __builtin_amdgcn_mfma_f32_16x16x32_bf16(b1, afr[rt][1], acc, 0, 0, 0);
            // lane holds codes kb+{0..3} for row rt*16+col
            float d0 = fmaf(-2.0f, acc[0], bn4[0]);
            float d1 = fmaf(-2.0f, acc[1], bn4[1]);
            float d2 = fmaf(-2.0f, acc[2], bn4[2]);
            float d3 = fmaf(-2.0f, acc[3], bn4[3]);
            float m = fminf(fminf(d0, d1), fminf(d2, d3));
            runmin[rt] = fminf(runmin[rt], m);
            const float lim = runmin[rt] + THR;
            if (d0 <= lim) { if (cnt[rt] < CAP) myl[rt * CAP + cnt[rt]] = (unsigned short)(kb + 0); ++cnt[rt]; }
            if (d1 <= lim) { if (cnt[rt] < CAP) myl[rt * CAP + cnt[rt]] = (unsigned short)(kb + 1); ++cnt[rt]; }
            if (d2 <= lim) { if (cnt[rt] < CAP) myl[rt * CAP + cnt[rt]] = (unsigned short)(kb + 2); ++cnt[rt]; }
            if (d3 <= lim) { if (cnt[rt] < CAP) myl[rt * CAP + cnt[rt]] = (unsigned short)(kb + 3); ++cnt[rt]; }
        }
    }

    // ---- np-bit-exact refine of own lists; quad-reduce; per-wave publish ----
    #pragma unroll
    for (int rt = 0; rt < RT_N; ++rt) {
        const int row = rt * 16 + col;
        const float* xr = x + (size_t)(r0 + row) * DIM;
        const float  an = anorm[row];
        unsigned long long best = ~0ULL;
        const int n = (cnt[rt] > CAP) ? CAP : cnt[rt];
        for (int j = 0; j < n; ++j) {
            const int k = myl[rt * CAP + j];
            unsigned long long key = np_key(xr, cb + (size_t)k * DIM, an, bnorm[k], k);
            best = (key < best) ? key : best;
        }
        unsigned long long o = __shfl_xor(best, 16, 64);   // merge quads (same col=row)
        best = (o < best) ? o : best;
        o = __shfl_xor(best, 32, 64);
        best = (o < best) ? o : best;
        int ov = (cnt[rt] > CAP) ? 1 : 0;
        ov |= __shfl_xor(ov, 16, 64);
        ov |= __shfl_xor(ov, 32, 64);
        if (quad == 0) { wkey[wv][row] = best; wovf[wv][row] = ov; }
    }
    __syncthreads();

    // ---- cross-wave merge ----
    if (tid < MTILE) {
        unsigned long long k0 = wkey[0][tid], k1 = wkey[1][tid];
        unsigned long long k2 = wkey[2][tid], k3 = wkey[3][tid];
        unsigned long long a = (k0 < k1) ? k0 : k1;
        unsigned long long b = (k2 < k3) ? k2 : k3;
        unsigned long long best = (a < b) ? a : b;
        int ov = wovf[0][tid] | wovf[1][tid] | wovf[2][tid] | wovf[3][tid];
        if (ov) {
            int s = atomicAdd(&ovfcnt, 1);
            ovfrows[s] = tid;
        } else {
            kstar[tid] = (int)(best & 0xFFFULL);
            lossd[tid] = (double)funmap32((unsigned int)(best >> 12));
        }
    }
    __syncthreads();

    // ---- wave-parallel exhaustive np fallback for overflowed rows (rare) ----
    const int ovfn = ovfcnt;
    for (int i = wv; i < ovfn; i += 4) {
        const int row = ovfrows[i];
        const float* xr2 = x + (size_t)(r0 + row) * DIM;
        const float an2 = anorm[row];
        unsigned long long b2 = ~0ULL;
        for (int j = 0; j < 16; ++j) {
            int k = lane * 16 + j;
            unsigned long long key = np_key(xr2, cb + (size_t)k * DIM, an2, bnorm[k], k);
            b2 = (key < b2) ? key : b2;
        }
        #pragma unroll
        for (int off = 1; off < 64; off <<= 1) {
            unsigned long long o = __shfl_xor(b2, off, 64);
            b2 = (o < b2) ? o : b2;
        }
        if (lane == 0) {
            kstar[row] = (int)(b2 & 0xFFFULL);
            lossd[row] = (double)funmap32((unsigned int)(b2 >> 12));
        }
    }
    __syncthreads();

    // ---- epilogue: indices (as float), transposed quantized, loss (verified) ----
    if (tid < MTILE) out_idx[r0 + tid] = (float)kstar[tid];

    const int bb = r0 / T_LEN;
    const int t0 = r0 % T_LEN;
    const int t  = tid & 127, half = tid >> 7;
    const int kt = kstar[t];
    #pragma unroll
    for (int it = 0; it < 32; ++it) {
        int d = it * 2 + half;
        out_q[((size_t)bb * DIM + d) * T_LEN + (t0 + t)] = cb[(size_t)kt * DIM + d];
    }

    if (tid < 64) {
        double v = lossd[tid] + lossd[tid + 64];
        #pragma unroll
        for (int off = 32; off > 0; off >>= 1) v += __shfl_down(v, off, 64);
        if (tid == 0) {
            if (use_partials) wsd[blockIdx.x] = v;
            else atomicAdd(wsd, v);
        }
    }
}

extern "C" void kernel_launch(void* const* d_in, const int* in_sizes, int n_in,
                              void* d_out, int out_size, void* d_ws, size_t ws_size,
                              hipStream_t stream) {
    const float* x  = (const float*)d_in[0];
    const float* cb = (const float*)d_in[1];
    float* out = (float*)d_out;

    const int n_x = in_sizes[0];           // 4194304
    const int n_rows = n_x / DIM;          // 65536
    const int n_blocks = n_rows / MTILE;   // 512

    float* out_q    = out;                    // [B, D, T]
    float* out_loss = out + (size_t)n_x;      // scalar
    float* out_idx  = out + (size_t)n_x + 1;  // [B, T] as float
    double* wsd = (double*)d_ws;

    const int use_partials = (ws_size >= (size_t)n_blocks * sizeof(double)) ? 1 : 0;
    if (!use_partials) vq_init_ws<<<1, 1, 0, stream>>>(wsd);
    vq_main<<<n_blocks, THREADS, 0, stream>>>(x, cb, out_q, out_idx, wsd, use_partials);
    if (use_partials) vq_finalize_part<<<1, 512, 0, stream>>>(wsd, out_loss, n_x);
    else vq_finalize_atomic<<<1, 1, 0, stream>>>(wsd, out_loss, n_x);
}

// Round 2
// 227.372 us; speedup vs baseline: 8.9919x; 8.9919x over previous
//
#include <hip/hip_runtime.h>

#define DIM 64
#define MTILE 128        // rows per block
#define THREADS 256
#define T_LEN 2048
#define WPITCH 68        // fp32 anorm staging window pitch (overlaid on pool)
#define THR 2e-3f        // capture margin (proven pairwise bound 1.53e-3)
#define CAP 8            // per-(lane,row-tile) candidate list capacity
#define RT_N 8           // row-tiles (16 rows each) per block
#define LSTRIDE 66       // shorts per thread list block: 132B = 33 dwords (odd -> all banks)

typedef __attribute__((ext_vector_type(8))) short short8;
typedef __attribute__((ext_vector_type(4))) float f32x4;

// monotone order-preserving map float -> u32
__device__ __forceinline__ unsigned int fmap32(float s) {
    unsigned int b = __float_as_uint(s);
    return (b & 0x80000000u) ? ~b : (b | 0x80000000u);
}
__device__ __forceinline__ float funmap32(unsigned int m) {
    unsigned int b = (m & 0x80000000u) ? (m & 0x7fffffffu) : ~m;
    return __uint_as_float(b);
}
// fp32 -> bf16 RTNE
__device__ __forceinline__ unsigned int f2bf(float f) {
    unsigned int u = __float_as_uint(f);
    return (u + 0x7FFFu + ((u >> 16) & 1u)) >> 16;
}
// numpy pairwise-sum (n=64 scalar blocked path) combine tree over 8 partials
__device__ __forceinline__ float np_combine8(const float* r) {
    return __fadd_rn(__fadd_rn(__fadd_rn(r[0], r[1]), __fadd_rn(r[2], r[3])),
                     __fadd_rn(__fadd_rn(r[4], r[5]), __fadd_rn(r[6], r[7])));
}
// numpy-bit-exact distance key for one (row, code) pair (verified r2-r6)
__device__ __forceinline__ unsigned long long np_key(
        const float* __restrict__ xr, const float* __restrict__ cr,
        float an, float bn, int k) {
    float acc = 0.0f;
    #pragma unroll
    for (int i = 0; i < DIM; ++i) acc = __fmaf_rn(xr[i], cr[i], acc);
    float t1 = __fadd_rn(an, bn);
    float d  = __fsub_rn(t1, __fmul_rn(2.0f, acc));
    return ((unsigned long long)fmap32(d) << 12) | (unsigned long long)k;
}

__global__ void vq_init_ws(double* ws) { ws[0] = 0.0; }

__global__ void vq_finalize_atomic(const double* __restrict__ ws,
                                   float* __restrict__ out_loss, int n_el) {
    out_loss[0] = (float)(1.25 * ws[0] / (double)n_el);
}

__global__ void vq_finalize_part(const double* __restrict__ ws,
                                 float* __restrict__ out_loss, int n_el) {
    __shared__ double red[8];
    double v = ws[threadIdx.x];
    #pragma unroll
    for (int off = 32; off > 0; off >>= 1) v += __shfl_down(v, off, 64);
    if ((threadIdx.x & 63) == 0) red[threadIdx.x >> 6] = v;
    __syncthreads();
    if (threadIdx.x == 0) {
        double s = 0.0;
        #pragma unroll
        for (int i = 0; i < 8; ++i) s += red[i];
        out_loss[0] = (float)(1.25 * s / (double)n_el);
    }
}

// Swapped-operand MFMA (codes as A-operand): lane col = row, regs = codes.
// Per-(wave,row) running min via 2 cross-quad shfl_xor per tile (256-code
// scope -> tight lim, tiny capture counts). Min-sweep + capture fully in
// registers; no main-loop barriers. Superset-safe: wave runmin >= global
// d~min. np-bit-exact refine on own short lists; rare overflowed rows fall
// back to wave-parallel exhaustive np scan.
__global__ __launch_bounds__(THREADS) void vq_main(
        const float* __restrict__ x,
        const float* __restrict__ cb,
        float* __restrict__ out_q,
        float* __restrict__ out_idx,
        double* __restrict__ wsd,
        int use_partials)
{
    // pool: candidate lists (256*66*2B = 33792B), overlaid with the fp32
    // anorm staging window (64*68*4B = 17408B) used only in the prologue.
    __shared__ alignas(16) char pool[THREADS * LSTRIDE * 2];
    __shared__ float  bnorm[1024];
    __shared__ float  anorm[MTILE];
    __shared__ int    kstar[MTILE];
    __shared__ double lossd[MTILE];
    __shared__ unsigned long long wkey[4][MTILE];
    __shared__ int    wovf[4][MTILE];
    __shared__ int    ovfrows[MTILE];
    __shared__ int    ovfcnt;

    const int tid  = threadIdx.x;
    const int lane = tid & 63;
    const int wv   = tid >> 6;         // wave 0..3
    const int col  = lane & 15;
    const int quad = lane >> 4;        // 0..3
    const int r0   = blockIdx.x * MTILE;

    if (tid == 0) ovfcnt = 0;

    // ---- B_k for all 1024 codes (numpy register routine, verified r2-r6) ----
    #pragma unroll
    for (int j = 0; j < 4; ++j) {
        int k = tid * 4 + j;
        const float4* c4 = (const float4*)(cb + (size_t)k * DIM);
        float r8[8];
        {
            float4 a = c4[0], b = c4[1];
            r8[0] = __fmul_rn(a.x, a.x); r8[1] = __fmul_rn(a.y, a.y);
            r8[2] = __fmul_rn(a.z, a.z); r8[3] = __fmul_rn(a.w, a.w);
            r8[4] = __fmul_rn(b.x, b.x); r8[5] = __fmul_rn(b.y, b.y);
            r8[6] = __fmul_rn(b.z, b.z); r8[7] = __fmul_rn(b.w, b.w);
        }
        #pragma unroll
        for (int m = 1; m < 8; ++m) {
            float4 a = c4[2 * m], b = c4[2 * m + 1];
            r8[0] = __fadd_rn(r8[0], __fmul_rn(a.x, a.x));
            r8[1] = __fadd_rn(r8[1], __fmul_rn(a.y, a.y));
            r8[2] = __fadd_rn(r8[2], __fmul_rn(a.z, a.z));
            r8[3] = __fadd_rn(r8[3], __fmul_rn(a.w, a.w));
            r8[4] = __fadd_rn(r8[4], __fmul_rn(b.x, b.x));
            r8[5] = __fadd_rn(r8[5], __fmul_rn(b.y, b.y));
            r8[6] = __fadd_rn(r8[6], __fmul_rn(b.z, b.z));
            r8[7] = __fadd_rn(r8[7], __fmul_rn(b.w, b.w));
        }
        bnorm[k] = np_combine8(r8);
    }

    // ---- A_n for 128 rows via fp32 window overlaid on pool (verified r2-r6) ----
    float* CSW = (float*)pool;
    const float4* x4 = (const float4*)x;
    for (int sb = 0; sb < 2; ++sb) {
        #pragma unroll
        for (int it = 0; it < 4; ++it) {
            int idx = it * THREADS + tid;
            int row = idx >> 4, f4 = idx & 15;
            float4 v = x4[(size_t)(r0 + sb * 64 + row) * 16 + f4];
            *(float4*)&CSW[row * WPITCH + f4 * 4] = v;
        }
        __syncthreads();
        for (int j = 0; j < 16; ++j) {
            int rl = wv * 16 + j;
            float v  = CSW[rl * WPITCH + lane];
            float pp = __fmul_rn(v, v);
            float r = __fadd_rn(pp, __shfl_down(pp, 8, 64));
            r = __fadd_rn(r, __shfl_down(pp, 16, 64));
            r = __fadd_rn(r, __shfl_down(pp, 24, 64));
            r = __fadd_rn(r, __shfl_down(pp, 32, 64));
            r = __fadd_rn(r, __shfl_down(pp, 40, 64));
            r = __fadd_rn(r, __shfl_down(pp, 48, 64));
            r = __fadd_rn(r, __shfl_down(pp, 56, 64));
            float rr[8];
            #pragma unroll
            for (int q = 0; q < 8; ++q) rr[q] = __shfl(r, q, 64);
            if (lane == 0) anorm[sb * 64 + rl] = np_combine8(rr);
        }
        __syncthreads();
    }

    // ---- A (row) fragments direct from global with in-lane bf16 convert ----
    // Layout: col = row-within-tile, quad*8+e (+kh*32) = k. Valid as either
    // MFMA operand (A/B lane layouts are symmetric for 16x16x32).
    short8 afr[RT_N][2];
    #pragma unroll
    for (int mt = 0; mt < RT_N; ++mt) {
        #pragma unroll
        for (int kh = 0; kh < 2; ++kh) {
            const float* ap = x + (size_t)(r0 + mt * 16 + col) * DIM + kh * 32 + quad * 8;
            float4 a = *(const float4*)ap;
            float4 b = *(const float4*)(ap + 4);
            short8 s;
            s[0] = (short)f2bf(a.x); s[1] = (short)f2bf(a.y);
            s[2] = (short)f2bf(a.z); s[3] = (short)f2bf(a.w);
            s[4] = (short)f2bf(b.x); s[5] = (short)f2bf(b.y);
            s[6] = (short)f2bf(b.z); s[7] = (short)f2bf(b.w);
            afr[mt][kh] = s;
        }
    }

    unsigned short* myl = (unsigned short*)pool + (size_t)tid * LSTRIDE;
    float runmin[RT_N];
    int   cnt[RT_N];
    #pragma unroll
    for (int rt = 0; rt < RT_N; ++rt) { runmin[rt] = 3.4e38f; cnt[rt] = 0; }

    // ---- main loop: this wave handles code-tiles kt = 4*t + wv (16 tiles) ----
    // Codes as FIRST mfma operand -> output regs index codes, col indexes row.
    // Code loads register-double-buffered; no barriers in this loop.
    const float* bp0 = cb + (size_t)(wv * 16 + col) * DIM + quad * 8;
    float4 pa = *(const float4*)(bp0);
    float4 pb = *(const float4*)(bp0 + 4);
    float4 pc = *(const float4*)(bp0 + 32);
    float4 pd = *(const float4*)(bp0 + 36);

    #pragma unroll 1
    for (int t = 0; t < 16; ++t) {
        const int kbase = (t * 4 + wv) * 16;
        float4 ca = pa, cb4 = pb, cc = pc, cd = pd;
        if (t < 15) {
            const float* nxt = bp0 + (size_t)(t + 1) * 4096;  // 4 tiles * 16 codes * 64
            pa = *(const float4*)(nxt);
            pb = *(const float4*)(nxt + 4);
            pc = *(const float4*)(nxt + 32);
            pd = *(const float4*)(nxt + 36);
        }
        short8 b0, b1;
        b0[0] = (short)f2bf(ca.x);  b0[1] = (short)f2bf(ca.y);
        b0[2] = (short)f2bf(ca.z);  b0[3] = (short)f2bf(ca.w);
        b0[4] = (short)f2bf(cb4.x); b0[5] = (short)f2bf(cb4.y);
        b0[6] = (short)f2bf(cb4.z); b0[7] = (short)f2bf(cb4.w);
        b1[0] = (short)f2bf(cc.x);  b1[1] = (short)f2bf(cc.y);
        b1[2] = (short)f2bf(cc.z);  b1[3] = (short)f2bf(cc.w);
        b1[4] = (short)f2bf(cd.x);  b1[5] = (short)f2bf(cd.y);
        b1[6] = (short)f2bf(cd.z);  b1[7] = (short)f2bf(cd.w);
        const f32x4 bn4 = *(const f32x4*)&bnorm[kbase + quad * 4];
        const int kb = kbase + quad * 4;

        #pragma unroll
        for (int rt = 0; rt < RT_N; ++rt) {
            f32x4 acc = {0.f, 0.f, 0.f, 0.f};
            acc = __builtin_amdgcn_mfma_f32_16x16x32_bf16(b0, afr[rt][0], acc, 0, 0, 0);
            acc = __builtin_amdgcn_mfma_f32_16x16x32_bf16(b1, afr[rt][1], acc, 0, 0, 0);
            // lane holds codes kb+{0..3} for row rt*16+col
            float d0 = fmaf(-2.0f, acc[0], bn4[0]);
            float d1 = fmaf(-2.0f, acc[1], bn4[1]);
            float d2 = fmaf(-2.0f, acc[2], bn4[2]);
            float d3 = fmaf(-2.0f, acc[3], bn4[3]);
            float m = fminf(fminf(d0, d1), fminf(d2, d3));
            // cross-quad merge: lanes {col, col^16, col^32, col^48} share a row
            float mw = fminf(m, __shfl_xor(m, 16, 64));
            mw = fminf(mw, __shfl_xor(mw, 32, 64));
            runmin[rt] = fminf(runmin[rt], mw);
            const float lim = runmin[rt] + THR;
            if (d0 <= lim) { if (cnt[rt] < CAP) myl[rt * CAP + cnt[rt]] = (unsigned short)(kb + 0); ++cnt[rt]; }
            if (d1 <= lim) { if (cnt[rt] < CAP) myl[rt * CAP + cnt[rt]] = (unsigned short)(kb + 1); ++cnt[rt]; }
            if (d2 <= lim) { if (cnt[rt] < CAP) myl[rt * CAP + cnt[rt]] = (unsigned short)(kb + 2); ++cnt[rt]; }
            if (d3 <= lim) { if (cnt[rt] < CAP) myl[rt * CAP + cnt[rt]] = (unsigned short)(kb + 3); ++cnt[rt]; }
        }
    }

    // ---- np-bit-exact refine of own lists; quad-reduce; per-wave publish ----
    #pragma unroll
    for (int rt = 0; rt < RT_N; ++rt) {
        const int row = rt * 16 + col;
        const float* xr = x + (size_t)(r0 + row) * DIM;
        const float  an = anorm[row];
        unsigned long long best = ~0ULL;
        const int n = (cnt[rt] > CAP) ? CAP : cnt[rt];
        for (int j = 0; j < n; ++j) {
            const int k = myl[rt * CAP + j];
            unsigned long long key = np_key(xr, cb + (size_t)k * DIM, an, bnorm[k], k);
            best = (key < best) ? key : best;
        }
        unsigned long long o = __shfl_xor(best, 16, 64);   // merge quads (same col=row)
        best = (o < best) ? o : best;
        o = __shfl_xor(best, 32, 64);
        best = (o < best) ? o : best;
        int ov = (cnt[rt] > CAP) ? 1 : 0;
        ov |= __shfl_xor(ov, 16, 64);
        ov |= __shfl_xor(ov, 32, 64);
        if (quad == 0) { wkey[wv][row] = best; wovf[wv][row] = ov; }
    }
    __syncthreads();

    // ---- cross-wave merge ----
    if (tid < MTILE) {
        unsigned long long k0 = wkey[0][tid], k1 = wkey[1][tid];
        unsigned long long k2 = wkey[2][tid], k3 = wkey[3][tid];
        unsigned long long a = (k0 < k1) ? k0 : k1;
        unsigned long long b = (k2 < k3) ? k2 : k3;
        unsigned long long best = (a < b) ? a : b;
        int ov = wovf[0][tid] | wovf[1][tid] | wovf[2][tid] | wovf[3][tid];
        if (ov) {
            int s = atomicAdd(&ovfcnt, 1);
            ovfrows[s] = tid;
        } else {
            kstar[tid] = (int)(best & 0xFFFULL);
            lossd[tid] = (double)funmap32((unsigned int)(best >> 12));
        }
    }
    __syncthreads();

    // ---- wave-parallel exhaustive np fallback for overflowed rows (rare) ----
    const int ovfn = ovfcnt;
    for (int i = wv; i < ovfn; i += 4) {
        const int row = ovfrows[i];
        const float* xr2 = x + (size_t)(r0 + row) * DIM;
        const float an2 = anorm[row];
        unsigned long long b2 = ~0ULL;
        for (int j = 0; j < 16; ++j) {
            int k = lane * 16 + j;
            unsigned long long key = np_key(xr2, cb + (size_t)k * DIM, an2, bnorm[k], k);
            b2 = (key < b2) ? key : b2;
        }
        #pragma unroll
        for (int off = 1; off < 64; off <<= 1) {
            unsigned long long o = __shfl_xor(b2, off, 64);
            b2 = (o < b2) ? o : b2;
        }
        if (lane == 0) {
            kstar[row] = (int)(b2 & 0xFFFULL);
            lossd[row] = (double)funmap32((unsigned int)(b2 >> 12));
        }
    }
    __syncthreads();

    // ---- epilogue: indices (as float), transposed quantized, loss (verified) ----
    if (tid < MTILE) out_idx[r0 + tid] = (float)kstar[tid];

    const int bb = r0 / T_LEN;
    const int t0 = r0 % T_LEN;
    const int t  = tid & 127, half = tid >> 7;
    const int kt = kstar[t];
    #pragma unroll
    for (int it = 0; it < 32; ++it) {
        int d = it * 2 + half;
        out_q[((size_t)bb * DIM + d) * T_LEN + (t0 + t)] = cb[(size_t)kt * DIM + d];
    }

    if (tid < 64) {
        double v = lossd[tid] + lossd[tid + 64];
        #pragma unroll
        for (int off = 32; off > 0; off >>= 1) v += __shfl_down(v, off, 64);
        if (tid == 0) {
            if (use_partials) wsd[blockIdx.x] = v;
            else atomicAdd(wsd, v);
        }
    }
}

extern "C" void kernel_launch(void* const* d_in, const int* in_sizes, int n_in,
                              void* d_out, int out_size, void* d_ws, size_t ws_size,
                              hipStream_t stream) {
    const float* x  = (const float*)d_in[0];
    const float* cb = (const float*)d_in[1];
    float* out = (float*)d_out;

    const int n_x = in_sizes[0];           // 4194304
    const int n_rows = n_x / DIM;          // 65536
    const int n_blocks = n_rows / MTILE;   // 512

    float* out_q    = out;                    // [B, D, T]
    float* out_loss = out + (size_t)n_x;      // scalar
    float* out_idx  = out + (size_t)n_x + 1;  // [B, T] as float
    double* wsd = (double*)d_ws;

    const int use_partials = (ws_size >= (size_t)n_blocks * sizeof(double)) ? 1 : 0;
    if (!use_partials) vq_init_ws<<<1, 1, 0, stream>>>(wsd);
    vq_main<<<n_blocks, THREADS, 0, stream>>>(x, cb, out_q, out_idx, wsd, use_partials);
    if (use_partials) vq_finalize_part<<<1, 512, 0, stream>>>(wsd, out_loss, n_x);
    else vq_finalize_atomic<<<1, 1, 0, stream>>>(wsd, out_loss, n_x);
}

// Round 3
// 195.502 us; speedup vs baseline: 10.4577x; 1.1630x over previous
//
#include <hip/hip_runtime.h>

#define DIM 64
#define MTILE 64         // rows per block (halved: 1024 blocks -> 4/CU occupancy)
#define THREADS 256
#define T_LEN 2048
#define WPITCH 68        // fp32 anorm staging window pitch (overlaid on pool)
#define THR 2e-3f        // capture margin (proven pairwise bound 1.53e-3)
#define CAP 8            // per-(lane,row-tile) candidate list capacity
#define RT_N 4           // row-tiles (16 rows each) per block
#define LSTRIDE 34       // shorts per thread list block: 68B = 17 dwords (odd -> all banks)

typedef __attribute__((ext_vector_type(8))) short short8;
typedef __attribute__((ext_vector_type(4))) float f32x4;

// monotone order-preserving map float -> u32
__device__ __forceinline__ unsigned int fmap32(float s) {
    unsigned int b = __float_as_uint(s);
    return (b & 0x80000000u) ? ~b : (b | 0x80000000u);
}
__device__ __forceinline__ float funmap32(unsigned int m) {
    unsigned int b = (m & 0x80000000u) ? (m & 0x7fffffffu) : ~m;
    return __uint_as_float(b);
}
// fp32 -> bf16 RTNE
__device__ __forceinline__ unsigned int f2bf(float f) {
    unsigned int u = __float_as_uint(f);
    return (u + 0x7FFFu + ((u >> 16) & 1u)) >> 16;
}
// numpy pairwise-sum (n=64 scalar blocked path) combine tree over 8 partials
__device__ __forceinline__ float np_combine8(const float* r) {
    return __fadd_rn(__fadd_rn(__fadd_rn(r[0], r[1]), __fadd_rn(r[2], r[3])),
                     __fadd_rn(__fadd_rn(r[4], r[5]), __fadd_rn(r[6], r[7])));
}
// numpy-bit-exact distance key for one (row, code) pair (verified r2-r6)
__device__ __forceinline__ unsigned long long np_key(
        const float* __restrict__ xr, const float* __restrict__ cr,
        float an, float bn, int k) {
    float acc = 0.0f;
    #pragma unroll
    for (int i = 0; i < DIM; ++i) acc = __fmaf_rn(xr[i], cr[i], acc);
    float t1 = __fadd_rn(an, bn);
    float d  = __fsub_rn(t1, __fmul_rn(2.0f, acc));
    return ((unsigned long long)fmap32(d) << 12) | (unsigned long long)k;
}

__global__ void vq_init_ws(double* ws) { ws[0] = 0.0; }

__global__ void vq_finalize_atomic(const double* __restrict__ ws,
                                   float* __restrict__ out_loss, int n_el) {
    out_loss[0] = (float)(1.25 * ws[0] / (double)n_el);
}

// reduces 1024 per-block partials (launched with 1024 threads)
__global__ void vq_finalize_part(const double* __restrict__ ws,
                                 float* __restrict__ out_loss, int n_el) {
    __shared__ double red[16];
    double v = ws[threadIdx.x];
    #pragma unroll
    for (int off = 32; off > 0; off >>= 1) v += __shfl_down(v, off, 64);
    if ((threadIdx.x & 63) == 0) red[threadIdx.x >> 6] = v;
    __syncthreads();
    if (threadIdx.x == 0) {
        double s = 0.0;
        #pragma unroll
        for (int i = 0; i < 16; ++i) s += red[i];
        out_loss[0] = (float)(1.25 * s / (double)n_el);
    }
}

// Swapped-operand MFMA (codes as A-operand): lane col = row, regs = codes.
// Register min-sweep + capture, no main-loop barriers. lim tightened across
// waves via LDS rowmin (atomicMin in order-preserving u32 space; racy reads
// are superset-safe: any observed value >= true d~min, so lim >= d~min+THR
// and each row's true argmin is always captured by its owner lane).
// np-bit-exact refine on own short lists; rare overflowed rows fall back
// to wave-parallel exhaustive np scan.
__global__ __launch_bounds__(THREADS) void vq_main(
        const float* __restrict__ x,
        const float* __restrict__ cb,
        float* __restrict__ out_q,
        float* __restrict__ out_idx,
        double* __restrict__ wsd,
        int use_partials)
{
    // pool: candidate lists (256*34*2B = 17408B), overlaid with the fp32
    // anorm staging window (64*68*4B = 17408B) used only in the prologue.
    __shared__ alignas(16) char pool[THREADS * LSTRIDE * 2];
    __shared__ float  bnorm[1024];
    __shared__ float  anorm[MTILE];
    __shared__ int    kstar[MTILE];
    __shared__ double lossd[MTILE];
    __shared__ unsigned int rowmin[MTILE];
    __shared__ unsigned long long wkey[4][MTILE];
    __shared__ int    wovf[4][MTILE];
    __shared__ int    ovfrows[MTILE];
    __shared__ int    ovfcnt;

    const int tid  = threadIdx.x;
    const int lane = tid & 63;
    const int wv   = tid >> 6;         // wave 0..3
    const int col  = lane & 15;
    const int quad = lane >> 4;        // 0..3
    const int r0   = blockIdx.x * MTILE;

    if (tid == 0) ovfcnt = 0;
    if (tid < MTILE) rowmin[tid] = 0xFFFFFFFFu;

    // ---- B_k for all 1024 codes (numpy register routine, verified r2-r6) ----
    #pragma unroll
    for (int j = 0; j < 4; ++j) {
        int k = tid * 4 + j;
        const float4* c4 = (const float4*)(cb + (size_t)k * DIM);
        float r8[8];
        {
            float4 a = c4[0], b = c4[1];
            r8[0] = __fmul_rn(a.x, a.x); r8[1] = __fmul_rn(a.y, a.y);
            r8[2] = __fmul_rn(a.z, a.z); r8[3] = __fmul_rn(a.w, a.w);
            r8[4] = __fmul_rn(b.x, b.x); r8[5] = __fmul_rn(b.y, b.y);
            r8[6] = __fmul_rn(b.z, b.z); r8[7] = __fmul_rn(b.w, b.w);
        }
        #pragma unroll
        for (int m = 1; m < 8; ++m) {
            float4 a = c4[2 * m], b = c4[2 * m + 1];
            r8[0] = __fadd_rn(r8[0], __fmul_rn(a.x, a.x));
            r8[1] = __fadd_rn(r8[1], __fmul_rn(a.y, a.y));
            r8[2] = __fadd_rn(r8[2], __fmul_rn(a.z, a.z));
            r8[3] = __fadd_rn(r8[3], __fmul_rn(a.w, a.w));
            r8[4] = __fadd_rn(r8[4], __fmul_rn(b.x, b.x));
            r8[5] = __fadd_rn(r8[5], __fmul_rn(b.y, b.y));
            r8[6] = __fadd_rn(r8[6], __fmul_rn(b.z, b.z));
            r8[7] = __fadd_rn(r8[7], __fmul_rn(b.w, b.w));
        }
        bnorm[k] = np_combine8(r8);
    }

    // ---- A_n for 64 rows via fp32 window overlaid on pool (verified r2-r6) ----
    float* CSW = (float*)pool;
    const float4* x4 = (const float4*)x;
    {
        #pragma unroll
        for (int it = 0; it < 4; ++it) {
            int idx = it * THREADS + tid;
            int row = idx >> 4, f4 = idx & 15;
            float4 v = x4[(size_t)(r0 + row) * 16 + f4];
            *(float4*)&CSW[row * WPITCH + f4 * 4] = v;
        }
        __syncthreads();
        for (int j = 0; j < 16; ++j) {
            int rl = wv * 16 + j;
            float v  = CSW[rl * WPITCH + lane];
            float pp = __fmul_rn(v, v);
            float r = __fadd_rn(pp, __shfl_down(pp, 8, 64));
            r = __fadd_rn(r, __shfl_down(pp, 16, 64));
            r = __fadd_rn(r, __shfl_down(pp, 24, 64));
            r = __fadd_rn(r, __shfl_down(pp, 32, 64));
            r = __fadd_rn(r, __shfl_down(pp, 40, 64));
            r = __fadd_rn(r, __shfl_down(pp, 48, 64));
            r = __fadd_rn(r, __shfl_down(pp, 56, 64));
            float rr[8];
            #pragma unroll
            for (int q = 0; q < 8; ++q) rr[q] = __shfl(r, q, 64);
            if (lane == 0) anorm[rl] = np_combine8(rr);
        }
        __syncthreads();
    }

    // ---- A (row) fragments direct from global with in-lane bf16 convert ----
    // Layout: col = row-within-tile, quad*8+e (+kh*32) = k. Valid as either
    // MFMA operand (A/B lane layouts are symmetric for 16x16x32).
    short8 afr[RT_N][2];
    #pragma unroll
    for (int mt = 0; mt < RT_N; ++mt) {
        #pragma unroll
        for (int kh = 0; kh < 2; ++kh) {
            const float* ap = x + (size_t)(r0 + mt * 16 + col) * DIM + kh * 32 + quad * 8;
            float4 a = *(const float4*)ap;
            float4 b = *(const float4*)(ap + 4);
            short8 s;
            s[0] = (short)f2bf(a.x); s[1] = (short)f2bf(a.y);
            s[2] = (short)f2bf(a.z); s[3] = (short)f2bf(a.w);
            s[4] = (short)f2bf(b.x); s[5] = (short)f2bf(b.y);
            s[6] = (short)f2bf(b.z); s[7] = (short)f2bf(b.w);
            afr[mt][kh] = s;
        }
    }

    unsigned short* myl = (unsigned short*)pool + (size_t)tid * LSTRIDE;
    float runmin[RT_N];
    int   cnt[RT_N];
    #pragma unroll
    for (int rt = 0; rt < RT_N; ++rt) { runmin[rt] = 3.4e38f; cnt[rt] = 0; }

    // ---- main loop: this wave handles code-tiles kt = 4*t + wv (16 tiles) ----
    // Codes as FIRST mfma operand -> output regs index codes, col indexes row.
    // Code loads register-double-buffered; no barriers in this loop.
    const float* bp0 = cb + (size_t)(wv * 16 + col) * DIM + quad * 8;
    float4 pa = *(const float4*)(bp0);
    float4 pb = *(const float4*)(bp0 + 4);
    float4 pc = *(const float4*)(bp0 + 32);
    float4 pd = *(const float4*)(bp0 + 36);

    #pragma unroll 1
    for (int t = 0; t < 16; ++t) {
        const int kbase = (t * 4 + wv) * 16;
        float4 ca = pa, cb4 = pb, cc = pc, cd = pd;
        if (t < 15) {
            const float* nxt = bp0 + (size_t)(t + 1) * 4096;  // 4 tiles * 16 codes * 64
            pa = *(const float4*)(nxt);
            pb = *(const float4*)(nxt + 4);
            pc = *(const float4*)(nxt + 32);
            pd = *(const float4*)(nxt + 36);
        }
        short8 b0, b1;
        b0[0] = (short)f2bf(ca.x);  b0[1] = (short)f2bf(ca.y);
        b0[2] = (short)f2bf(ca.z);  b0[3] = (short)f2bf(ca.w);
        b0[4] = (short)f2bf(cb4.x); b0[5] = (short)f2bf(cb4.y);
        b0[6] = (short)f2bf(cb4.z); b0[7] = (short)f2bf(cb4.w);
        b1[0] = (short)f2bf(cc.x);  b1[1] = (short)f2bf(cc.y);
        b1[2] = (short)f2bf(cc.z);  b1[3] = (short)f2bf(cc.w);
        b1[4] = (short)f2bf(cd.x);  b1[5] = (short)f2bf(cd.y);
        b1[6] = (short)f2bf(cd.z);  b1[7] = (short)f2bf(cd.w);
        const f32x4 bn4 = *(const f32x4*)&bnorm[kbase + quad * 4];
        const int kb = kbase + quad * 4;

        #pragma unroll
        for (int rt = 0; rt < RT_N; ++rt) {
            f32x4 acc = {0.f, 0.f, 0.f, 0.f};
            acc = __builtin_amdgcn_mfma_f32_16x16x32_bf16(b0, afr[rt][0], acc, 0, 0, 0);
            acc = __builtin_amdgcn_mfma_f32_16x16x32_bf16(b1, afr[rt][1], acc, 0, 0, 0);
            // lane holds codes kb+{0..3} for row rt*16+col
            float d0 = fmaf(-2.0f, acc[0], bn4[0]);
            float d1 = fmaf(-2.0f, acc[1], bn4[1]);
            float d2 = fmaf(-2.0f, acc[2], bn4[2]);
            float d3 = fmaf(-2.0f, acc[3], bn4[3]);
            float m = fminf(fminf(d0, d1), fminf(d2, d3));
            // cross-quad merge: lanes {col, col^16, col^32, col^48} share a row
            float mw = fminf(m, __shfl_xor(m, 16, 64));
            mw = fminf(mw, __shfl_xor(mw, 32, 64));
            float rm = fminf(runmin[rt], mw);
            runmin[rt] = rm;
            const int row = rt * 16 + col;
            if (quad == 0) atomicMin(&rowmin[row], fmap32(rm));
            float g = funmap32(rowmin[row]);   // racy read; INF maps to NaN, fminf-safe
            const float lim = fminf(rm, g) + THR;
            if (d0 <= lim) { if (cnt[rt] < CAP) myl[rt * CAP + cnt[rt]] = (unsigned short)(kb + 0); ++cnt[rt]; }
            if (d1 <= lim) { if (cnt[rt] < CAP) myl[rt * CAP + cnt[rt]] = (unsigned short)(kb + 1); ++cnt[rt]; }
            if (d2 <= lim) { if (cnt[rt] < CAP) myl[rt * CAP + cnt[rt]] = (unsigned short)(kb + 2); ++cnt[rt]; }
            if (d3 <= lim) { if (cnt[rt] < CAP) myl[rt * CAP + cnt[rt]] = (unsigned short)(kb + 3); ++cnt[rt]; }
        }
    }

    // ---- np-bit-exact refine of own lists; quad-reduce; per-wave publish ----
    #pragma unroll
    for (int rt = 0; rt < RT_N; ++rt) {
        const int row = rt * 16 + col;
        const float* xr = x + (size_t)(r0 + row) * DIM;
        const float  an = anorm[row];
        unsigned long long best = ~0ULL;
        const int n = (cnt[rt] > CAP) ? CAP : cnt[rt];
        for (int j = 0; j < n; ++j) {
            const int k = myl[rt * CAP + j];
            unsigned long long key = np_key(xr, cb + (size_t)k * DIM, an, bnorm[k], k);
            best = (key < best) ? key : best;
        }
        unsigned long long o = __shfl_xor(best, 16, 64);   // merge quads (same col=row)
        best = (o < best) ? o : best;
        o = __shfl_xor(best, 32, 64);
        best = (o < best) ? o : best;
        int ov = (cnt[rt] > CAP) ? 1 : 0;
        ov |= __shfl_xor(ov, 16, 64);
        ov |= __shfl_xor(ov, 32, 64);
        if (quad == 0) { wkey[wv][row] = best; wovf[wv][row] = ov; }
    }
    __syncthreads();

    // ---- cross-wave merge ----
    if (tid < MTILE) {
        unsigned long long k0 = wkey[0][tid], k1 = wkey[1][tid];
        unsigned long long k2 = wkey[2][tid], k3 = wkey[3][tid];
        unsigned long long a = (k0 < k1) ? k0 : k1;
        unsigned long long b = (k2 < k3) ? k2 : k3;
        unsigned long long best = (a < b) ? a : b;
        int ov = wovf[0][tid] | wovf[1][tid] | wovf[2][tid] | wovf[3][tid];
        if (ov) {
            int s = atomicAdd(&ovfcnt, 1);
            ovfrows[s] = tid;
        } else {
            kstar[tid] = (int)(best & 0xFFFULL);
            lossd[tid] = (double)funmap32((unsigned int)(best >> 12));
        }
    }
    __syncthreads();

    // ---- wave-parallel exhaustive np fallback for overflowed rows (rare) ----
    const int ovfn = ovfcnt;
    for (int i = wv; i < ovfn; i += 4) {
        const int row = ovfrows[i];
        const float* xr2 = x + (size_t)(r0 + row) * DIM;
        const float an2 = anorm[row];
        unsigned long long b2 = ~0ULL;
        for (int j = 0; j < 16; ++j) {
            int k = lane * 16 + j;
            unsigned long long key = np_key(xr2, cb + (size_t)k * DIM, an2, bnorm[k], k);
            b2 = (key < b2) ? key : b2;
        }
        #pragma unroll
        for (int off = 1; off < 64; off <<= 1) {
            unsigned long long o = __shfl_xor(b2, off, 64);
            b2 = (o < b2) ? o : b2;
        }
        if (lane == 0) {
            kstar[row] = (int)(b2 & 0xFFFULL);
            lossd[row] = (double)funmap32((unsigned int)(b2 >> 12));
        }
    }
    __syncthreads();

    // ---- epilogue: indices (as float), transposed quantized, loss (verified) ----
    if (tid < MTILE) out_idx[r0 + tid] = (float)kstar[tid];

    const int bb = r0 / T_LEN;
    const int t0 = r0 % T_LEN;
    const int t  = tid & 63, part = tid >> 6;
    const int kt = kstar[t];
    #pragma unroll
    for (int it = 0; it < 16; ++it) {
        int d = it * 4 + part;
        out_q[((size_t)bb * DIM + d) * T_LEN + (t0 + t)] = cb[(size_t)kt * DIM + d];
    }

    if (tid < 64) {
        double v = lossd[tid];
        #pragma unroll
        for (int off = 32; off > 0; off >>= 1) v += __shfl_down(v, off, 64);
        if (tid == 0) {
            if (use_partials) wsd[blockIdx.x] = v;
            else atomicAdd(wsd, v);
        }
    }
}

extern "C" void kernel_launch(void* const* d_in, const int* in_sizes, int n_in,
                              void* d_out, int out_size, void* d_ws, size_t ws_size,
                              hipStream_t stream) {
    const float* x  = (const float*)d_in[0];
    const float* cb = (const float*)d_in[1];
    float* out = (float*)d_out;

    const int n_x = in_sizes[0];           // 4194304
    const int n_rows = n_x / DIM;          // 65536
    const int n_blocks = n_rows / MTILE;   // 1024

    float* out_q    = out;                    // [B, D, T]
    float* out_loss = out + (size_t)n_x;      // scalar
    float* out_idx  = out + (size_t)n_x + 1;  // [B, T] as float
    double* wsd = (double*)d_ws;

    const int use_partials = (ws_size >= (size_t)n_blocks * sizeof(double)) ? 1 : 0;
    if (!use_partials) vq_init_ws<<<1, 1, 0, stream>>>(wsd);
    vq_main<<<n_blocks, THREADS, 0, stream>>>(x, cb, out_q, out_idx, wsd, use_partials);
    if (use_partials) vq_finalize_part<<<1, 1024, 0, stream>>>(wsd, out_loss, n_x);
    else vq_finalize_atomic<<<1, 1, 0, stream>>>(wsd, out_loss, n_x);
}

// Round 4
// 190.176 us; speedup vs baseline: 10.7506x; 1.0280x over previous
//
#include <hip/hip_runtime.h>

#define DIM 64
#define MTILE 64         // rows per block -> 1024 blocks
#define THREADS 256
#define T_LEN 2048
#define THR 2e-3f        // capture margin (proven pairwise bound 1.53e-3)
#define RCAP 32          // per-row candidate list capacity
#define RT_N 4           // row-tiles (16 rows each) per block
#define XP 65            // xstage/cstage pitch in floats (conflict-free scalar reads)
#define RLP 33           // rlist pitch in u32 (conflict-free per-row access)

typedef __attribute__((ext_vector_type(8))) short short8;
typedef __attribute__((ext_vector_type(4))) float f32x4;

// monotone order-preserving map float -> u32
__device__ __forceinline__ unsigned int fmap32(float s) {
    unsigned int b = __float_as_uint(s);
    return (b & 0x80000000u) ? ~b : (b | 0x80000000u);
}
__device__ __forceinline__ float funmap32(unsigned int m) {
    unsigned int b = (m & 0x80000000u) ? (m & 0x7fffffffu) : ~m;
    return __uint_as_float(b);
}
// fp32 -> bf16 RTNE
__device__ __forceinline__ unsigned int f2bf(float f) {
    unsigned int u = __float_as_uint(f);
    return (u + 0x7FFFu + ((u >> 16) & 1u)) >> 16;
}
// numpy pairwise-sum (n=64 scalar blocked path) combine tree over 8 partials
__device__ __forceinline__ float np_combine8(const float* r) {
    return __fadd_rn(__fadd_rn(__fadd_rn(r[0], r[1]), __fadd_rn(r[2], r[3])),
                     __fadd_rn(__fadd_rn(r[4], r[5]), __fadd_rn(r[6], r[7])));
}
// numpy n=64 squared-norm register routine (verified r2-r6; used for bnorm AND anorm —
// bit-identical partial/order structure to the previously-verified shfl path)
__device__ __forceinline__ float np_norm64(const float* p) {
    const float4* c4 = (const float4*)p;
    float r8[8];
    {
        float4 a = c4[0], b = c4[1];
        r8[0] = __fmul_rn(a.x, a.x); r8[1] = __fmul_rn(a.y, a.y);
        r8[2] = __fmul_rn(a.z, a.z); r8[3] = __fmul_rn(a.w, a.w);
        r8[4] = __fmul_rn(b.x, b.x); r8[5] = __fmul_rn(b.y, b.y);
        r8[6] = __fmul_rn(b.z, b.z); r8[7] = __fmul_rn(b.w, b.w);
    }
    #pragma unroll
    for (int m = 1; m < 8; ++m) {
        float4 a = c4[2 * m], b = c4[2 * m + 1];
        r8[0] = __fadd_rn(r8[0], __fmul_rn(a.x, a.x));
        r8[1] = __fadd_rn(r8[1], __fmul_rn(a.y, a.y));
        r8[2] = __fadd_rn(r8[2], __fmul_rn(a.z, a.z));
        r8[3] = __fadd_rn(r8[3], __fmul_rn(a.w, a.w));
        r8[4] = __fadd_rn(r8[4], __fmul_rn(b.x, b.x));
        r8[5] = __fadd_rn(r8[5], __fmul_rn(b.y, b.y));
        r8[6] = __fadd_rn(r8[6], __fmul_rn(b.z, b.z));
        r8[7] = __fadd_rn(r8[7], __fmul_rn(b.w, b.w));
    }
    return np_combine8(r8);
}
// numpy-bit-exact distance key for one (row, code) pair (verified r2-r6).
// Pointers may be LDS or global (generic) — bits are identical either way.
__device__ __forceinline__ unsigned long long np_key(
        const float* xr, const float* cr, float an, float bn, int k) {
    float acc = 0.0f;
    #pragma unroll
    for (int i = 0; i < DIM; ++i) acc = __fmaf_rn(xr[i], cr[i], acc);
    float t1 = __fadd_rn(an, bn);
    float d  = __fsub_rn(t1, __fmul_rn(2.0f, acc));
    return ((unsigned long long)fmap32(d) << 12) | (unsigned long long)k;
}

__global__ void vq_init_ws(double* ws) { ws[0] = 0.0; }

__global__ void vq_finalize_atomic(const double* __restrict__ ws,
                                   float* __restrict__ out_loss, int n_el) {
    out_loss[0] = (float)(1.25 * ws[0] / (double)n_el);
}

// reduces 1024 per-block partials (launched with 1024 threads)
__global__ void vq_finalize_part(const double* __restrict__ ws,
                                 float* __restrict__ out_loss, int n_el) {
    __shared__ double red[16];
    double v = ws[threadIdx.x];
    #pragma unroll
    for (int off = 32; off > 0; off >>= 1) v += __shfl_down(v, off, 64);
    if ((threadIdx.x & 63) == 0) red[threadIdx.x >> 6] = v;
    __syncthreads();
    if (threadIdx.x == 0) {
        double s = 0.0;
        #pragma unroll
        for (int i = 0; i < 16; ++i) s += red[i];
        out_loss[0] = (float)(1.25 * s / (double)n_el);
    }
}

// Swapped-operand MFMA scan with register capture into per-row LDS lists
// (d~ truncated + k packed in u32). After the scan: post-filter by FINAL
// rowmin (truncation rounds d~ down -> superset-safe), then a cooperative
// refine: per candidate rank j, 4 threads/row stage the code row into LDS
// (coalesced float4), one thread/row runs the np-bit-exact key chain from
// conflict-free LDS. Overflowed rows (rare) fall back to exhaustive np scan.
__global__ __launch_bounds__(THREADS) void vq_main(
        const float* __restrict__ x,
        const float* __restrict__ cb,
        float* __restrict__ out_q,
        float* __restrict__ out_idx,
        double* __restrict__ wsd,
        int use_partials)
{
    __shared__ float xstage[MTILE * XP];     // 16640 B, x rows (exact fp32 bits)
    __shared__ float cstage[MTILE * XP];     // 16640 B, staged candidate rows
    __shared__ float bnorm[1024];            // 4096 B
    __shared__ unsigned int rlist[MTILE * RLP]; // 8448 B, packed (d~trunc | k)
    __shared__ int   rcnt[MTILE];
    __shared__ int   ncnt[MTILE];
    __shared__ unsigned int rowmin[MTILE];
    __shared__ float anorm[MTILE];
    __shared__ int   kstar[MTILE];
    __shared__ double lossd[MTILE];
    __shared__ int   ovfrows[MTILE];
    __shared__ int   ovfcnt, rmax;

    const int tid  = threadIdx.x;
    const int lane = tid & 63;
    const int wv   = tid >> 6;         // wave 0..3
    const int col  = lane & 15;
    const int quad = lane >> 4;        // 0..3
    const int r0   = blockIdx.x * MTILE;

    if (tid == 0) { ovfcnt = 0; rmax = 0; }
    if (tid < MTILE) { rcnt[tid] = 0; rowmin[tid] = 0xFFFFFFFFu; }

    // ---- B_k for all 1024 codes (numpy register routine, verified) ----
    #pragma unroll
    for (int j = 0; j < 4; ++j) {
        int k = tid * 4 + j;
        bnorm[k] = np_norm64(cb + (size_t)k * DIM);
    }
    // ---- A_n per thread (same verified routine, bit-identical partial order) ----
    if (tid < MTILE) anorm[tid] = np_norm64(x + (size_t)(r0 + tid) * DIM);

    // ---- stage x rows into LDS (exact bits; pitch 65 -> conflict-free reads) ----
    {
        const int rr = tid >> 2, part = tid & 3;
        const float4* xs = (const float4*)(x + (size_t)(r0 + rr) * DIM + part * 16);
        float4 v0 = xs[0], v1 = xs[1], v2 = xs[2], v3 = xs[3];
        float* dst = &xstage[rr * XP + part * 16];
        dst[0]  = v0.x; dst[1]  = v0.y; dst[2]  = v0.z; dst[3]  = v0.w;
        dst[4]  = v1.x; dst[5]  = v1.y; dst[6]  = v1.z; dst[7]  = v1.w;
        dst[8]  = v2.x; dst[9]  = v2.y; dst[10] = v2.z; dst[11] = v2.w;
        dst[12] = v3.x; dst[13] = v3.y; dst[14] = v3.z; dst[15] = v3.w;
    }

    // ---- A (row) fragments direct from global with in-lane bf16 convert ----
    short8 afr[RT_N][2];
    #pragma unroll
    for (int mt = 0; mt < RT_N; ++mt) {
        #pragma unroll
        for (int kh = 0; kh < 2; ++kh) {
            const float* ap = x + (size_t)(r0 + mt * 16 + col) * DIM + kh * 32 + quad * 8;
            float4 a = *(const float4*)ap;
            float4 b = *(const float4*)(ap + 4);
            short8 s;
            s[0] = (short)f2bf(a.x); s[1] = (short)f2bf(a.y);
            s[2] = (short)f2bf(a.z); s[3] = (short)f2bf(a.w);
            s[4] = (short)f2bf(b.x); s[5] = (short)f2bf(b.y);
            s[6] = (short)f2bf(b.z); s[7] = (short)f2bf(b.w);
            afr[mt][kh] = s;
        }
    }

    float runmin[RT_N];
    #pragma unroll
    for (int rt = 0; rt < RT_N; ++rt) runmin[rt] = 3.4e38f;

    __syncthreads();   // bnorm/rcnt/rowmin ready

    // ---- main loop: wave handles code-tiles kt = 4*t + wv; reg dbuf loads ----
    const float* bp0 = cb + (size_t)(wv * 16 + col) * DIM + quad * 8;
    float4 pa = *(const float4*)(bp0);
    float4 pb = *(const float4*)(bp0 + 4);
    float4 pc = *(const float4*)(bp0 + 32);
    float4 pd = *(const float4*)(bp0 + 36);

    #pragma unroll 1
    for (int t = 0; t < 16; ++t) {
        const int kbase = (t * 4 + wv) * 16;
        float4 ca = pa, cb4 = pb, cc = pc, cd = pd;
        if (t < 15) {
            const float* nxt = bp0 + (size_t)(t + 1) * 4096;  // 4 tiles * 16 codes * 64
            pa = *(const float4*)(nxt);
            pb = *(const float4*)(nxt + 4);
            pc = *(const float4*)(nxt + 32);
            pd = *(const float4*)(nxt + 36);
        }
        short8 b0, b1;
        b0[0] = (short)f2bf(ca.x);  b0[1] = (short)f2bf(ca.y);
        b0[2] = (short)f2bf(ca.z);  b0[3] = (short)f2bf(ca.w);
        b0[4] = (short)f2bf(cb4.x); b0[5] = (short)f2bf(cb4.y);
        b0[6] = (short)f2bf(cb4.z); b0[7] = (short)f2bf(cb4.w);
        b1[0] = (short)f2bf(cc.x);  b1[1] = (short)f2bf(cc.y);
        b1[2] = (short)f2bf(cc.z);  b1[3] = (short)f2bf(cc.w);
        b1[4] = (short)f2bf(cd.x);  b1[5] = (short)f2bf(cd.y);
        b1[6] = (short)f2bf(cd.z);  b1[7] = (short)f2bf(cd.w);
        const f32x4 bn4 = *(const f32x4*)&bnorm[kbase + quad * 4];
        const int kb = kbase + quad * 4;

        // compute all 4 row-tiles first (independent chains)
        float d[RT_N][4];
        float m[RT_N];
        #pragma unroll
        for (int rt = 0; rt < RT_N; ++rt) {
            f32x4 acc = {0.f, 0.f, 0.f, 0.f};
            acc = __builtin_amdgcn_mfma_f32_16x16x32_bf16(b0, afr[rt][0], acc, 0, 0, 0);
            acc = __builtin_amdgcn_mfma_f32_16x16x32_bf16(b1, afr[rt][1], acc, 0, 0, 0);
            d[rt][0] = fmaf(-2.0f, acc[0], bn4[0]);
            d[rt][1] = fmaf(-2.0f, acc[1], bn4[1]);
            d[rt][2] = fmaf(-2.0f, acc[2], bn4[2]);
            d[rt][3] = fmaf(-2.0f, acc[3], bn4[3]);
            m[rt] = fminf(fminf(d[rt][0], d[rt][1]), fminf(d[rt][2], d[rt][3]));
        }
        // batched cross-quad merges (one swizzle-latency exposure per level)
        float mw[RT_N];
        #pragma unroll
        for (int rt = 0; rt < RT_N; ++rt) mw[rt] = fminf(m[rt], __shfl_xor(m[rt], 16, 64));
        #pragma unroll
        for (int rt = 0; rt < RT_N; ++rt) mw[rt] = fminf(mw[rt], __shfl_xor(mw[rt], 32, 64));
        #pragma unroll
        for (int rt = 0; rt < RT_N; ++rt) {
            runmin[rt] = fminf(runmin[rt], mw[rt]);
            if (quad == 0) atomicMin(&rowmin[rt * 16 + col], fmap32(runmin[rt]));
        }
        float lim[RT_N];
        #pragma unroll
        for (int rt = 0; rt < RT_N; ++rt) {
            float g = funmap32(rowmin[rt * 16 + col]);  // racy read; NaN-safe via fminf
            lim[rt] = fminf(runmin[rt], g) + THR;
        }
        // rare captures -> per-row LDS list (atomic append, packed d~|k)
        #pragma unroll
        for (int rt = 0; rt < RT_N; ++rt) {
            const int row = rt * 16 + col;
            #pragma unroll
            for (int e = 0; e < 4; ++e) {
                if (d[rt][e] <= lim[rt]) {
                    int s = atomicAdd(&rcnt[row], 1);
                    if (s < RCAP)
                        rlist[row * RLP + s] =
                            (fmap32(d[rt][e]) & 0xFFFFFC00u) | (unsigned int)(kb + e);
                }
            }
        }
    }

    __syncthreads();   // rowmin final, rlist complete

    // ---- compact: filter by FINAL rowmin + THR (truncation-safe superset) ----
    if (tid < MTILE) {
        const int r = tid;
        int n = rcnt[r];
        int ov = (n > RCAP) ? 1 : 0;
        if (ov) n = 0;
        const float flim = funmap32(rowmin[r]) + THR;
        int mcnt = 0;
        for (int j = 0; j < n; ++j) {
            unsigned int e = rlist[r * RLP + j];
            if (funmap32(e & 0xFFFFFC00u) <= flim)
                rlist[r * RLP + mcnt++] = e;
        }
        if (!ov && mcnt == 0) ov = 1;   // defensive (cannot happen: argmin always passes)
        ncnt[r] = ov ? 0 : mcnt;
        if (!ov) atomicMax(&rmax, mcnt);
        if (ov) { int s = atomicAdd(&ovfcnt, 1); ovfrows[s] = r; }
    }
    __syncthreads();

    // ---- cooperative np-bit-exact refine: stage (4 thr/row) + chain (1 thr/row) ----
    const int jmax = rmax;
    unsigned long long best = ~0ULL;
    {
        const int rr = tid >> 2, part = tid & 3;
        for (int j = 0; j < jmax; ++j) {
            if (j < ncnt[rr]) {
                int k = (int)(rlist[rr * RLP + j] & 1023u);
                const float4* cp = (const float4*)(cb + (size_t)k * DIM + part * 16);
                float4 v0 = cp[0], v1 = cp[1], v2 = cp[2], v3 = cp[3];
                float* dst = &cstage[rr * XP + part * 16];
                dst[0]  = v0.x; dst[1]  = v0.y; dst[2]  = v0.z; dst[3]  = v0.w;
                dst[4]  = v1.x; dst[5]  = v1.y; dst[6]  = v1.z; dst[7]  = v1.w;
                dst[8]  = v2.x; dst[9]  = v2.y; dst[10] = v2.z; dst[11] = v2.w;
                dst[12] = v3.x; dst[13] = v3.y; dst[14] = v3.z; dst[15] = v3.w;
            }
            __syncthreads();
            if (tid < MTILE && j < ncnt[tid]) {
                int k = (int)(rlist[tid * RLP + j] & 1023u);
                unsigned long long key = np_key(&xstage[tid * XP], &cstage[tid * XP],
                                                anorm[tid], bnorm[k], k);
                best = (key < best) ? key : best;
            }
            __syncthreads();
        }
    }
    if (tid < MTILE && ncnt[tid] > 0) {
        kstar[tid] = (int)(best & 0xFFFULL);
        lossd[tid] = (double)funmap32((unsigned int)(best >> 12));
    }
    __syncthreads();

    // ---- wave-parallel exhaustive np fallback for overflowed rows (rare) ----
    const int ovfn = ovfcnt;
    for (int i = wv; i < ovfn; i += 4) {
        const int row = ovfrows[i];
        const float* xr2 = &xstage[row * XP];   // LDS broadcast reads
        const float an2 = anorm[row];
        unsigned long long b2 = ~0ULL;
        for (int j = 0; j < 16; ++j) {
            int k = lane * 16 + j;
            unsigned long long key = np_key(xr2, cb + (size_t)k * DIM, an2, bnorm[k], k);
            b2 = (key < b2) ? key : b2;
        }
        #pragma unroll
        for (int off = 1; off < 64; off <<= 1) {
            unsigned long long o = __shfl_xor(b2, off, 64);
            b2 = (o < b2) ? o : b2;
        }
        if (lane == 0) {
            kstar[row] = (int)(b2 & 0xFFFULL);
            lossd[row] = (double)funmap32((unsigned int)(b2 >> 12));
        }
    }
    __syncthreads();

    // ---- epilogue: indices (as float), transposed quantized, loss (verified) ----
    if (tid < MTILE) out_idx[r0 + tid] = (float)kstar[tid];

    const int bb = r0 / T_LEN;
    const int t0 = r0 % T_LEN;
    const int t  = tid & 63, part = tid >> 6;
    const int kt = kstar[t];
    #pragma unroll
    for (int it = 0; it < 16; ++it) {
        int d = it * 4 + part;
        out_q[((size_t)bb * DIM + d) * T_LEN + (t0 + t)] = cb[(size_t)kt * DIM + d];
    }

    if (tid < 64) {
        double v = lossd[tid];
        #pragma unroll
        for (int off = 32; off > 0; off >>= 1) v += __shfl_down(v, off, 64);
        if (tid == 0) {
            if (use_partials) wsd[blockIdx.x] = v;
            else atomicAdd(wsd, v);
        }
    }
}

extern "C" void kernel_launch(void* const* d_in, const int* in_sizes, int n_in,
                              void* d_out, int out_size, void* d_ws, size_t ws_size,
                              hipStream_t stream) {
    const float* x  = (const float*)d_in[0];
    const float* cb = (const float*)d_in[1];
    float* out = (float*)d_out;

    const int n_x = in_sizes[0];           // 4194304
    const int n_rows = n_x / DIM;          // 65536
    const int n_blocks = n_rows / MTILE;   // 1024

    float* out_q    = out;                    // [B, D, T]
    float* out_loss = out + (size_t)n_x;      // scalar
    float* out_idx  = out + (size_t)n_x + 1;  // [B, T] as float
    double* wsd = (double*)d_ws;

    const int use_partials = (ws_size >= (size_t)n_blocks * sizeof(double)) ? 1 : 0;
    if (!use_partials) vq_init_ws<<<1, 1, 0, stream>>>(wsd);
    vq_main<<<n_blocks, THREADS, 0, stream>>>(x, cb, out_q, out_idx, wsd, use_partials);
    if (use_partials) vq_finalize_part<<<1, 1024, 0, stream>>>(wsd, out_loss, n_x);
    else vq_finalize_atomic<<<1, 1, 0, stream>>>(wsd, out_loss, n_x);
}

// Round 5
// 173.922 us; speedup vs baseline: 11.7553x; 1.0935x over previous
//
#include <hip/hip_runtime.h>

#define DIM 64
#define MTILE 64         // rows per block -> 1024 blocks
#define THREADS 256
#define T_LEN 2048
#define SMARG 1e-3f      // s-space capture margin (d-space bound 1.59e-3/2 = 8e-4 needed)
#define RCAP 32          // per-row candidate list capacity
#define RT_N 4           // row-tiles (16 rows each) per block
#define XP 68            // xstage pitch in floats (272B: 16B-aligned for float4)
#define RLP 33           // rlist pitch in u32

typedef __attribute__((ext_vector_type(8))) short short8;
typedef __attribute__((ext_vector_type(4))) float f32x4;

// monotone order-preserving map float -> u32
__device__ __forceinline__ unsigned int fmap32(float s) {
    unsigned int b = __float_as_uint(s);
    return (b & 0x80000000u) ? ~b : (b | 0x80000000u);
}
__device__ __forceinline__ float funmap32(unsigned int m) {
    unsigned int b = (m & 0x80000000u) ? (m & 0x7fffffffu) : ~m;
    return __uint_as_float(b);
}
// fp32 -> bf16 RTNE
__device__ __forceinline__ unsigned int f2bf(float f) {
    unsigned int u = __float_as_uint(f);
    return (u + 0x7FFFu + ((u >> 16) & 1u)) >> 16;
}
// numpy pairwise-sum (n=64 scalar blocked path) combine tree over 8 partials
__device__ __forceinline__ float np_combine8(const float* r) {
    return __fadd_rn(__fadd_rn(__fadd_rn(r[0], r[1]), __fadd_rn(r[2], r[3])),
                     __fadd_rn(__fadd_rn(r[4], r[5]), __fadd_rn(r[6], r[7])));
}
// numpy n=64 squared-norm register routine (verified r2-r6). Generic pointer
// (works on LDS xstage rows); float4 accesses must be 16B-aligned.
__device__ __forceinline__ float np_norm64(const float* p) {
    const float4* c4 = (const float4*)p;
    float r8[8];
    {
        float4 a = c4[0], b = c4[1];
        r8[0] = __fmul_rn(a.x, a.x); r8[1] = __fmul_rn(a.y, a.y);
        r8[2] = __fmul_rn(a.z, a.z); r8[3] = __fmul_rn(a.w, a.w);
        r8[4] = __fmul_rn(b.x, b.x); r8[5] = __fmul_rn(b.y, b.y);
        r8[6] = __fmul_rn(b.z, b.z); r8[7] = __fmul_rn(b.w, b.w);
    }
    #pragma unroll
    for (int m = 1; m < 8; ++m) {
        float4 a = c4[2 * m], b = c4[2 * m + 1];
        r8[0] = __fadd_rn(r8[0], __fmul_rn(a.x, a.x));
        r8[1] = __fadd_rn(r8[1], __fmul_rn(a.y, a.y));
        r8[2] = __fadd_rn(r8[2], __fmul_rn(a.z, a.z));
        r8[3] = __fadd_rn(r8[3], __fmul_rn(a.w, a.w));
        r8[4] = __fadd_rn(r8[4], __fmul_rn(b.x, b.x));
        r8[5] = __fadd_rn(r8[5], __fmul_rn(b.y, b.y));
        r8[6] = __fadd_rn(r8[6], __fmul_rn(b.z, b.z));
        r8[7] = __fadd_rn(r8[7], __fmul_rn(b.w, b.w));
    }
    return np_combine8(r8);
}
// numpy-bit-exact distance key with LAZY np-exact bn: loads the code row to
// registers once, computes bn with the identical np_norm64 partial/order
// structure, then the verified serial 64-FMA dot chain. xr may be LDS.
__device__ __forceinline__ unsigned long long np_key_full(
        const float* xr, const float* cr, float an, int k) {
    float4 c4[16];
    #pragma unroll
    for (int i = 0; i < 16; ++i) c4[i] = ((const float4*)cr)[i];
    float r8[8];
    {
        float4 a = c4[0], b = c4[1];
        r8[0] = __fmul_rn(a.x, a.x); r8[1] = __fmul_rn(a.y, a.y);
        r8[2] = __fmul_rn(a.z, a.z); r8[3] = __fmul_rn(a.w, a.w);
        r8[4] = __fmul_rn(b.x, b.x); r8[5] = __fmul_rn(b.y, b.y);
        r8[6] = __fmul_rn(b.z, b.z); r8[7] = __fmul_rn(b.w, b.w);
    }
    #pragma unroll
    for (int m = 1; m < 8; ++m) {
        float4 a = c4[2 * m], b = c4[2 * m + 1];
        r8[0] = __fadd_rn(r8[0], __fmul_rn(a.x, a.x));
        r8[1] = __fadd_rn(r8[1], __fmul_rn(a.y, a.y));
        r8[2] = __fadd_rn(r8[2], __fmul_rn(a.z, a.z));
        r8[3] = __fadd_rn(r8[3], __fmul_rn(a.w, a.w));
        r8[4] = __fadd_rn(r8[4], __fmul_rn(b.x, b.x));
        r8[5] = __fadd_rn(r8[5], __fmul_rn(b.y, b.y));
        r8[6] = __fadd_rn(r8[6], __fmul_rn(b.z, b.z));
        r8[7] = __fadd_rn(r8[7], __fmul_rn(b.w, b.w));
    }
    float bn = np_combine8(r8);
    float acc = 0.0f;
    #pragma unroll
    for (int i = 0; i < 16; ++i) {
        acc = __fmaf_rn(xr[4 * i + 0], c4[i].x, acc);
        acc = __fmaf_rn(xr[4 * i + 1], c4[i].y, acc);
        acc = __fmaf_rn(xr[4 * i + 2], c4[i].z, acc);
        acc = __fmaf_rn(xr[4 * i + 3], c4[i].w, acc);
    }
    float t1 = __fadd_rn(an, bn);
    float d  = __fsub_rn(t1, __fmul_rn(2.0f, acc));
    return ((unsigned long long)fmap32(d) << 12) | (unsigned long long)k;
}

__global__ void vq_init_ws(double* ws) { ws[0] = 0.0; }

__global__ void vq_finalize_atomic(const double* __restrict__ ws,
                                   float* __restrict__ out_loss, int n_el) {
    out_loss[0] = (float)(1.25 * ws[0] / (double)n_el);
}

// reduces 1024 per-block partials (launched with 1024 threads)
__global__ void vq_finalize_part(const double* __restrict__ ws,
                                 float* __restrict__ out_loss, int n_el) {
    __shared__ double red[16];
    double v = ws[threadIdx.x];
    #pragma unroll
    for (int off = 32; off > 0; off >>= 1) v += __shfl_down(v, off, 64);
    if ((threadIdx.x & 63) == 0) red[threadIdx.x >> 6] = v;
    __syncthreads();
    if (threadIdx.x == 0) {
        double s = 0.0;
        #pragma unroll
        for (int i = 0; i < 16; ++i) s += red[i];
        out_loss[0] = (float)(1.25 * s / (double)n_el);
    }
}

// bnorm-free scan: s = bf16-dot(x,c); d~ = an + bn - 2s with bn <= 6.1e-5 <<
// THR, so maximizing s is capture-equivalent (margin 1.59e-3 < 2e-3 absorbed).
// No codebook gather prologue. Capture -> per-row LDS lists (packed s|k),
// post-filtered by final rowsmax; per-row-thread np-bit-exact refine with
// lazy register bn. Overflowed rows (rare) -> wave-parallel exhaustive scan.
__global__ __launch_bounds__(THREADS) void vq_main(
        const float* __restrict__ x,
        const float* __restrict__ cb,
        float* __restrict__ out_q,
        float* __restrict__ out_idx,
        double* __restrict__ wsd,
        int use_partials)
{
    __shared__ float xstage[MTILE * XP];        // 17408 B, x rows (exact bits)
    __shared__ unsigned int rlist[MTILE * RLP]; // 8448 B
    __shared__ int   rcnt[MTILE];
    __shared__ unsigned int rowsmax[MTILE];     // fmap32(s) space, atomicMax
    __shared__ float anorm[MTILE];
    __shared__ int   kstar[MTILE];
    __shared__ double lossd[MTILE];
    __shared__ int   ovfrows[MTILE];
    __shared__ int   ovfcnt;

    const int tid  = threadIdx.x;
    const int lane = tid & 63;
    const int wv   = tid >> 6;         // wave 0..3
    const int col  = lane & 15;
    const int quad = lane >> 4;        // 0..3
    const int r0   = blockIdx.x * MTILE;

    if (tid == 0) ovfcnt = 0;
    if (tid < MTILE) { rcnt[tid] = 0; rowsmax[tid] = 0u; }

    // ---- stage x rows into LDS, coalesced (exact fp32 bits) ----
    {
        const int rr = tid >> 2, part = tid & 3;
        const float4* xs = (const float4*)(x + (size_t)(r0 + rr) * DIM + part * 16);
        float4 v0 = xs[0], v1 = xs[1], v2 = xs[2], v3 = xs[3];
        float* dst = &xstage[rr * XP + part * 16];
        *(float4*)&dst[0]  = v0;
        *(float4*)&dst[4]  = v1;
        *(float4*)&dst[8]  = v2;
        *(float4*)&dst[12] = v3;
    }
    __syncthreads();

    // ---- A_n from staged rows (np-exact; LDS float4 reads, 16B-aligned) ----
    if (tid < MTILE) anorm[tid] = np_norm64(&xstage[tid * XP]);

    // ---- A (row) fragments from LDS with in-lane bf16 convert ----
    short8 afr[RT_N][2];
    #pragma unroll
    for (int mt = 0; mt < RT_N; ++mt) {
        #pragma unroll
        for (int kh = 0; kh < 2; ++kh) {
            const float* ap = &xstage[(mt * 16 + col) * XP + kh * 32 + quad * 8];
            float4 a = *(const float4*)ap;
            float4 b = *(const float4*)(ap + 4);
            short8 s;
            s[0] = (short)f2bf(a.x); s[1] = (short)f2bf(a.y);
            s[2] = (short)f2bf(a.z); s[3] = (short)f2bf(a.w);
            s[4] = (short)f2bf(b.x); s[5] = (short)f2bf(b.y);
            s[6] = (short)f2bf(b.z); s[7] = (short)f2bf(b.w);
            afr[mt][kh] = s;
        }
    }

    float runsmax[RT_N];
    #pragma unroll
    for (int rt = 0; rt < RT_N; ++rt) runsmax[rt] = -3.4e38f;

    // ---- main scan: wave handles code-tiles kt = 4*t + wv; reg dbuf loads ----
    const float* bp0 = cb + (size_t)(wv * 16 + col) * DIM + quad * 8;
    float4 pa = *(const float4*)(bp0);
    float4 pb = *(const float4*)(bp0 + 4);
    float4 pc = *(const float4*)(bp0 + 32);
    float4 pd = *(const float4*)(bp0 + 36);

    #pragma unroll 1
    for (int t = 0; t < 16; ++t) {
        const int kb = (t * 4 + wv) * 16 + quad * 4;
        float4 ca = pa, cb4 = pb, cc = pc, cd = pd;
        if (t < 15) {
            const float* nxt = bp0 + (size_t)(t + 1) * 4096;  // 4 tiles * 16 codes * 64
            pa = *(const float4*)(nxt);
            pb = *(const float4*)(nxt + 4);
            pc = *(const float4*)(nxt + 32);
            pd = *(const float4*)(nxt + 36);
        }
        short8 b0, b1;
        b0[0] = (short)f2bf(ca.x);  b0[1] = (short)f2bf(ca.y);
        b0[2] = (short)f2bf(ca.z);  b0[3] = (short)f2bf(ca.w);
        b0[4] = (short)f2bf(cb4.x); b0[5] = (short)f2bf(cb4.y);
        b0[6] = (short)f2bf(cb4.z); b0[7] = (short)f2bf(cb4.w);
        b1[0] = (short)f2bf(cc.x);  b1[1] = (short)f2bf(cc.y);
        b1[2] = (short)f2bf(cc.z);  b1[3] = (short)f2bf(cc.w);
        b1[4] = (short)f2bf(cd.x);  b1[5] = (short)f2bf(cd.y);
        b1[6] = (short)f2bf(cd.z);  b1[7] = (short)f2bf(cd.w);

        float s[RT_N][4];
        float m[RT_N];
        #pragma unroll
        for (int rt = 0; rt < RT_N; ++rt) {
            f32x4 acc = {0.f, 0.f, 0.f, 0.f};
            acc = __builtin_amdgcn_mfma_f32_16x16x32_bf16(b0, afr[rt][0], acc, 0, 0, 0);
            acc = __builtin_amdgcn_mfma_f32_16x16x32_bf16(b1, afr[rt][1], acc, 0, 0, 0);
            s[rt][0] = acc[0]; s[rt][1] = acc[1];
            s[rt][2] = acc[2]; s[rt][3] = acc[3];
            m[rt] = fmaxf(fmaxf(s[rt][0], s[rt][1]), fmaxf(s[rt][2], s[rt][3]));
        }
        // batched cross-quad max merges (lanes {col, col^16, col^32, col^48})
        float mw[RT_N];
        #pragma unroll
        for (int rt = 0; rt < RT_N; ++rt) mw[rt] = fmaxf(m[rt], __shfl_xor(m[rt], 16, 64));
        #pragma unroll
        for (int rt = 0; rt < RT_N; ++rt) mw[rt] = fmaxf(mw[rt], __shfl_xor(mw[rt], 32, 64));
        #pragma unroll
        for (int rt = 0; rt < RT_N; ++rt) runsmax[rt] = fmaxf(runsmax[rt], mw[rt]);
        if ((t & 3) == 3) {   // periodic cross-wave tighten (racy, superset-safe)
            #pragma unroll
            for (int rt = 0; rt < RT_N; ++rt)
                if (quad == 0) atomicMax(&rowsmax[rt * 16 + col], fmap32(runsmax[rt]));
            #pragma unroll
            for (int rt = 0; rt < RT_N; ++rt) {
                float g = funmap32(rowsmax[rt * 16 + col]);  // 0u -> NaN, fmaxf-safe
                runsmax[rt] = fmaxf(runsmax[rt], g);
            }
        }
        #pragma unroll
        for (int rt = 0; rt < RT_N; ++rt) {
            const int row = rt * 16 + col;
            const float cut = runsmax[rt] - SMARG;
            #pragma unroll
            for (int e = 0; e < 4; ++e) {
                if (s[rt][e] >= cut) {
                    int p = atomicAdd(&rcnt[row], 1);
                    if (p < RCAP)
                        rlist[row * RLP + p] =
                            (fmap32(s[rt][e]) & 0xFFFFFC00u) | (unsigned int)(kb + e);
                }
            }
        }
    }

    __syncthreads();   // rowsmax final (all waves folded at t=15), rlist complete

    // ---- per-row compact + np-bit-exact refine (no barriers; 64 handler
    //      threads spread across all 4 waves; lazy register bn) ----
    if ((tid & 3) == 0) {
        const int r = tid >> 2;
        int n = rcnt[r];
        int ov = (n > RCAP) ? 1 : 0;
        unsigned long long best = ~0ULL;
        if (!ov) {
            // stored s truncated DOWN by <= ~1e-6 << margin slack 2e-4: the
            // true argmin (s* >= smax - 8e-4) always passes this filter.
            const float cutf = funmap32(rowsmax[r]) - SMARG;
            const float an = anorm[r];
            const float* xr = &xstage[r * XP];
            int kept = 0;
            for (int j = 0; j < n; ++j) {
                unsigned int e = rlist[r * RLP + j];
                if (funmap32(e & 0xFFFFFC00u) >= cutf) {
                    int k = (int)(e & 1023u);
                    unsigned long long key = np_key_full(xr, cb + (size_t)k * DIM, an, k);
                    best = (key < best) ? key : best;
                    ++kept;
                }
            }
            if (kept == 0) ov = 1;   // defensive (cannot happen: argmin passes)
        }
        if (ov) {
            int si = atomicAdd(&ovfcnt, 1);
            ovfrows[si] = r;
        } else {
            kstar[r] = (int)(best & 0xFFFULL);
            lossd[r] = (double)funmap32((unsigned int)(best >> 12));
        }
    }
    __syncthreads();

    // ---- wave-parallel exhaustive np fallback for overflowed rows (rare) ----
    const int ovfn = ovfcnt;
    for (int i = wv; i < ovfn; i += 4) {
        const int row = ovfrows[i];
        const float* xr2 = &xstage[row * XP];   // same-address LDS broadcasts
        const float an2 = anorm[row];
        unsigned long long b2 = ~0ULL;
        for (int j = 0; j < 16; ++j) {
            int k = lane * 16 + j;
            unsigned long long key = np_key_full(xr2, cb + (size_t)k * DIM, an2, k);
            b2 = (key < b2) ? key : b2;
        }
        #pragma unroll
        for (int off = 1; off < 64; off <<= 1) {
            unsigned long long o = __shfl_xor(b2, off, 64);
            b2 = (o < b2) ? o : b2;
        }
        if (lane == 0) {
            kstar[row] = (int)(b2 & 0xFFFULL);
            lossd[row] = (double)funmap32((unsigned int)(b2 >> 12));
        }
    }
    __syncthreads();

    // ---- epilogue: indices (as float), transposed quantized, loss (verified) ----
    if (tid < MTILE) out_idx[r0 + tid] = (float)kstar[tid];

    const int bb = r0 / T_LEN;
    const int t0 = r0 % T_LEN;
    const int t  = tid & 63, part = tid >> 6;
    const int kt = kstar[t];
    #pragma unroll
    for (int it = 0; it < 16; ++it) {
        int d = it * 4 + part;
        out_q[((size_t)bb * DIM + d) * T_LEN + (t0 + t)] = cb[(size_t)kt * DIM + d];
    }

    if (tid < 64) {
        double v = lossd[tid];
        #pragma unroll
        for (int off = 32; off > 0; off >>= 1) v += __shfl_down(v, off, 64);
        if (tid == 0) {
            if (use_partials) wsd[blockIdx.x] = v;
            else atomicAdd(wsd, v);
        }
    }
}

extern "C" void kernel_launch(void* const* d_in, const int* in_sizes, int n_in,
                              void* d_out, int out_size, void* d_ws, size_t ws_size,
                              hipStream_t stream) {
    const float* x  = (const float*)d_in[0];
    const float* cb = (const float*)d_in[1];
    float* out = (float*)d_out;

    const int n_x = in_sizes[0];           // 4194304
    const int n_rows = n_x / DIM;          // 65536
    const int n_blocks = n_rows / MTILE;   // 1024

    float* out_q    = out;                    // [B, D, T]
    float* out_loss = out + (size_t)n_x;      // scalar
    float* out_idx  = out + (size_t)n_x + 1;  // [B, T] as float
    double* wsd = (double*)d_ws;

    const int use_partials = (ws_size >= (size_t)n_blocks * sizeof(double)) ? 1 : 0;
    if (!use_partials) vq_init_ws<<<1, 1, 0, stream>>>(wsd);
    vq_main<<<n_blocks, THREADS, 0, stream>>>(x, cb, out_q, out_idx, wsd, use_partials);
    if (use_partials) vq_finalize_part<<<1, 1024, 0, stream>>>(wsd, out_loss, n_x);
    else vq_finalize_atomic<<<1, 1, 0, stream>>>(wsd, out_loss, n_x);
}

// Round 6
// 131.132 us; speedup vs baseline: 15.5911x; 1.3263x over previous
//
#include <hip/hip_runtime.h>

#define DIM 64
#define MTILE 64         // rows per block -> 1024 blocks
#define THREADS 256
#define T_LEN 2048
#define SMARG 1e-3f      // s-space capture margin (needs 7.95e-4: pairwise 1.53e-3/2 + bn/2)
#define RCAP 16          // per-row candidate list capacity (expected ~2-3 used)
#define RT_N 4           // row-tiles (16 rows each) per block
#define XP 68            // xstage pitch in floats (272B = 17*16B, float4-aligned rows)
#define RLP 17           // rlist pitch in ushorts

typedef __attribute__((ext_vector_type(8))) short short8;
typedef __attribute__((ext_vector_type(4))) short short4v;
typedef __attribute__((ext_vector_type(4))) float f32x4;

// monotone order-preserving map float -> u32
__device__ __forceinline__ unsigned int fmap32(float s) {
    unsigned int b = __float_as_uint(s);
    return (b & 0x80000000u) ? ~b : (b | 0x80000000u);
}
__device__ __forceinline__ float funmap32(unsigned int m) {
    unsigned int b = (m & 0x80000000u) ? (m & 0x7fffffffu) : ~m;
    return __uint_as_float(b);
}
// fp32 -> bf16 RTNE
__device__ __forceinline__ unsigned int f2bf(float f) {
    unsigned int u = __float_as_uint(f);
    return (u + 0x7FFFu + ((u >> 16) & 1u)) >> 16;
}
// numpy pairwise-sum (n=64 scalar blocked path) combine tree over 8 partials
__device__ __forceinline__ float np_combine8(const float* r) {
    return __fadd_rn(__fadd_rn(__fadd_rn(r[0], r[1]), __fadd_rn(r[2], r[3])),
                     __fadd_rn(__fadd_rn(r[4], r[5]), __fadd_rn(r[6], r[7])));
}
// numpy n=64 squared-norm register routine (verified r2-r6). Generic pointer
// (works on LDS xstage rows); float4 accesses must be 16B-aligned.
__device__ __forceinline__ float np_norm64(const float* p) {
    const float4* c4 = (const float4*)p;
    float r8[8];
    {
        float4 a = c4[0], b = c4[1];
        r8[0] = __fmul_rn(a.x, a.x); r8[1] = __fmul_rn(a.y, a.y);
        r8[2] = __fmul_rn(a.z, a.z); r8[3] = __fmul_rn(a.w, a.w);
        r8[4] = __fmul_rn(b.x, b.x); r8[5] = __fmul_rn(b.y, b.y);
        r8[6] = __fmul_rn(b.z, b.z); r8[7] = __fmul_rn(b.w, b.w);
    }
    #pragma unroll
    for (int m = 1; m < 8; ++m) {
        float4 a = c4[2 * m], b = c4[2 * m + 1];
        r8[0] = __fadd_rn(r8[0], __fmul_rn(a.x, a.x));
        r8[1] = __fadd_rn(r8[1], __fmul_rn(a.y, a.y));
        r8[2] = __fadd_rn(r8[2], __fmul_rn(a.z, a.z));
        r8[3] = __fadd_rn(r8[3], __fmul_rn(a.w, a.w));
        r8[4] = __fadd_rn(r8[4], __fmul_rn(b.x, b.x));
        r8[5] = __fadd_rn(r8[5], __fmul_rn(b.y, b.y));
        r8[6] = __fadd_rn(r8[6], __fmul_rn(b.z, b.z));
        r8[7] = __fadd_rn(r8[7], __fmul_rn(b.w, b.w));
    }
    return np_combine8(r8);
}
// numpy-bit-exact distance key with LAZY np-exact bn (verified r5): loads the
// fp32 code row to registers once, computes bn with the identical np_norm64
// partial/order structure, then the verified serial 64-FMA dot chain.
__device__ __forceinline__ unsigned long long np_key_full(
        const float* xr, const float* cr, float an, int k) {
    float4 c4[16];
    #pragma unroll
    for (int i = 0; i < 16; ++i) c4[i] = ((const float4*)cr)[i];
    float r8[8];
    {
        float4 a = c4[0], b = c4[1];
        r8[0] = __fmul_rn(a.x, a.x); r8[1] = __fmul_rn(a.y, a.y);
        r8[2] = __fmul_rn(a.z, a.z); r8[3] = __fmul_rn(a.w, a.w);
        r8[4] = __fmul_rn(b.x, b.x); r8[5] = __fmul_rn(b.y, b.y);
        r8[6] = __fmul_rn(b.z, b.z); r8[7] = __fmul_rn(b.w, b.w);
    }
    #pragma unroll
    for (int m = 1; m < 8; ++m) {
        float4 a = c4[2 * m], b = c4[2 * m + 1];
        r8[0] = __fadd_rn(r8[0], __fmul_rn(a.x, a.x));
        r8[1] = __fadd_rn(r8[1], __fmul_rn(a.y, a.y));
        r8[2] = __fadd_rn(r8[2], __fmul_rn(a.z, a.z));
        r8[3] = __fadd_rn(r8[3], __fmul_rn(a.w, a.w));
        r8[4] = __fadd_rn(r8[4], __fmul_rn(b.x, b.x));
        r8[5] = __fadd_rn(r8[5], __fmul_rn(b.y, b.y));
        r8[6] = __fadd_rn(r8[6], __fmul_rn(b.z, b.z));
        r8[7] = __fadd_rn(r8[7], __fmul_rn(b.w, b.w));
    }
    float bn = np_combine8(r8);
    float acc = 0.0f;
    #pragma unroll
    for (int i = 0; i < 16; ++i) {
        acc = __fmaf_rn(xr[4 * i + 0], c4[i].x, acc);
        acc = __fmaf_rn(xr[4 * i + 1], c4[i].y, acc);
        acc = __fmaf_rn(xr[4 * i + 2], c4[i].z, acc);
        acc = __fmaf_rn(xr[4 * i + 3], c4[i].w, acc);
    }
    float t1 = __fadd_rn(an, bn);
    float d  = __fsub_rn(t1, __fmul_rn(2.0f, acc));
    return ((unsigned long long)fmap32(d) << 12) | (unsigned long long)k;
}

__global__ void vq_init_ws(double* ws) { ws[0] = 0.0; }

__global__ void vq_finalize_atomic(const double* __restrict__ ws,
                                   float* __restrict__ out_loss, int n_el) {
    out_loss[0] = (float)(1.25 * ws[0] / (double)n_el);
}

// reduces 1024 per-block partials (launched with 1024 threads)
__global__ void vq_finalize_part(const double* __restrict__ ws,
                                 float* __restrict__ out_loss, int n_el) {
    __shared__ double red[16];
    double v = ws[threadIdx.x];
    #pragma unroll
    for (int off = 32; off > 0; off >>= 1) v += __shfl_down(v, off, 64);
    if ((threadIdx.x & 63) == 0) red[threadIdx.x >> 6] = v;
    __syncthreads();
    if (threadIdx.x == 0) {
        double s = 0.0;
        #pragma unroll
        for (int i = 0; i < 16; ++i) s += red[i];
        out_loss[0] = (float)(1.25 * s / (double)n_el);
    }
}

// one-time fp32 -> bf16 codebook conversion into workspace (RTNE, identical
// f2bf as the scan; MFMA inputs bit-identical to in-kernel conversion).
__global__ void vq_cvt_cb(const float* __restrict__ cb,
                          unsigned short* __restrict__ cbbf) {
    const int i = blockIdx.x * 256 + threadIdx.x;   // 16384 threads * 4 elems
    float4 v = *(const float4*)(cb + (size_t)i * 4);
    short4v o;
    o[0] = (short)f2bf(v.x); o[1] = (short)f2bf(v.y);
    o[2] = (short)f2bf(v.z); o[3] = (short)f2bf(v.w);
    *(short4v*)(cbbf + (size_t)i * 4) = o;
}

// Two-pass bnorm-free scan (s = bf16-dot; maximizing s is capture-equivalent,
// margin 7.95e-4 < SMARG, proven r4/r5). Pass 1: load->MFMA->fmax only (no
// shfl/atomics/branches). One merge gives exact final per-row smax. Pass 2:
// recompute s (MFMA ~free), capture vs fixed cut smax-SMARG (~2-3 hits/row)
// into per-row lists. Refine: 64 row-threads, np-bit-exact lazy-bn keys.
template<int BF16CB>
__global__ __launch_bounds__(THREADS) void vq_main(
        const float* __restrict__ x,
        const float* __restrict__ cb,
        const unsigned short* __restrict__ cbbf,
        float* __restrict__ out_q,
        float* __restrict__ out_idx,
        double* __restrict__ wsd,
        int use_partials)
{
    __shared__ float xstage[MTILE * XP];        // 17408 B, x rows (exact bits)
    __shared__ float wsm[4][MTILE];             // per-wave row smax
    __shared__ unsigned short rlist[MTILE * RLP];
    __shared__ int   rcnt[MTILE];
    __shared__ float anorm[MTILE];
    __shared__ int   kstar[MTILE];
    __shared__ double lossd[MTILE];
    __shared__ int   ovfrows[MTILE];
    __shared__ int   ovfcnt;

    const int tid  = threadIdx.x;
    const int lane = tid & 63;
    const int wv   = tid >> 6;         // wave 0..3
    const int col  = lane & 15;
    const int quad = lane >> 4;        // 0..3
    const int r0   = blockIdx.x * MTILE;

    if (tid == 0) ovfcnt = 0;
    if (tid < MTILE) rcnt[tid] = 0;

    // ---- stage x rows into LDS, coalesced (exact fp32 bits) ----
    {
        const int rr = tid >> 2, part = tid & 3;
        const float4* xs = (const float4*)(x + (size_t)(r0 + rr) * DIM + part * 16);
        float4 v0 = xs[0], v1 = xs[1], v2 = xs[2], v3 = xs[3];
        float* dst = &xstage[rr * XP + part * 16];
        *(float4*)&dst[0]  = v0;
        *(float4*)&dst[4]  = v1;
        *(float4*)&dst[8]  = v2;
        *(float4*)&dst[12] = v3;
    }
    __syncthreads();

    // ---- A_n from staged rows (np-exact) ----
    if (tid < MTILE) anorm[tid] = np_norm64(&xstage[tid * XP]);

    // ---- A (row) fragments from LDS with in-lane bf16 convert ----
    short8 afr[RT_N][2];
    #pragma unroll
    for (int mt = 0; mt < RT_N; ++mt) {
        #pragma unroll
        for (int kh = 0; kh < 2; ++kh) {
            const float* ap = &xstage[(mt * 16 + col) * XP + kh * 32 + quad * 8];
            float4 a = *(const float4*)ap;
            float4 b = *(const float4*)(ap + 4);
            short8 s;
            s[0] = (short)f2bf(a.x); s[1] = (short)f2bf(a.y);
            s[2] = (short)f2bf(a.z); s[3] = (short)f2bf(a.w);
            s[4] = (short)f2bf(b.x); s[5] = (short)f2bf(b.y);
            s[6] = (short)f2bf(b.z); s[7] = (short)f2bf(b.w);
            afr[mt][kh] = s;
        }
    }

    // per-lane base pointers for this wave's code tiles (kt = 4t + wv)
    const unsigned short* bq0 = cbbf + (size_t)(wv * 16 + col) * DIM + quad * 8;
    const float*          bp0 = cb   + (size_t)(wv * 16 + col) * DIM + quad * 8;

    // ================= PASS 1: pure max scan =================
    float runsmax[RT_N];
    #pragma unroll
    for (int rt = 0; rt < RT_N; ++rt) runsmax[rt] = -3.4e38f;
    {
        short8 nb0, nb1;
        float4 pa, pb, pc, pd;
        if constexpr (BF16CB) {
            nb0 = *(const short8*)(bq0);
            nb1 = *(const short8*)(bq0 + 32);
        } else {
            pa = *(const float4*)(bp0);      pb = *(const float4*)(bp0 + 4);
            pc = *(const float4*)(bp0 + 32); pd = *(const float4*)(bp0 + 36);
        }
        #pragma unroll 1
        for (int t = 0; t < 16; ++t) {
            short8 b0, b1;
            if constexpr (BF16CB) {
                b0 = nb0; b1 = nb1;
                if (t < 15) {
                    const unsigned short* nx = bq0 + (size_t)(t + 1) * 4096;
                    nb0 = *(const short8*)(nx);
                    nb1 = *(const short8*)(nx + 32);
                }
            } else {
                float4 ca = pa, cb4 = pb, cc = pc, cd = pd;
                if (t < 15) {
                    const float* nx = bp0 + (size_t)(t + 1) * 4096;
                    pa = *(const float4*)(nx);      pb = *(const float4*)(nx + 4);
                    pc = *(const float4*)(nx + 32); pd = *(const float4*)(nx + 36);
                }
                b0[0] = (short)f2bf(ca.x);  b0[1] = (short)f2bf(ca.y);
                b0[2] = (short)f2bf(ca.z);  b0[3] = (short)f2bf(ca.w);
                b0[4] = (short)f2bf(cb4.x); b0[5] = (short)f2bf(cb4.y);
                b0[6] = (short)f2bf(cb4.z); b0[7] = (short)f2bf(cb4.w);
                b1[0] = (short)f2bf(cc.x);  b1[1] = (short)f2bf(cc.y);
                b1[2] = (short)f2bf(cc.z);  b1[3] = (short)f2bf(cc.w);
                b1[4] = (short)f2bf(cd.x);  b1[5] = (short)f2bf(cd.y);
                b1[6] = (short)f2bf(cd.z);  b1[7] = (short)f2bf(cd.w);
            }
            #pragma unroll
            for (int rt = 0; rt < RT_N; ++rt) {
                f32x4 acc = {0.f, 0.f, 0.f, 0.f};
                acc = __builtin_amdgcn_mfma_f32_16x16x32_bf16(b0, afr[rt][0], acc, 0, 0, 0);
                acc = __builtin_amdgcn_mfma_f32_16x16x32_bf16(b1, afr[rt][1], acc, 0, 0, 0);
                runsmax[rt] = fmaxf(runsmax[rt],
                    fmaxf(fmaxf(acc[0], acc[1]), fmaxf(acc[2], acc[3])));
            }
        }
    }
    // merge: quads (same row) then waves via LDS -> exact final smax per row
    #pragma unroll
    for (int rt = 0; rt < RT_N; ++rt) {
        float mw = fmaxf(runsmax[rt], __shfl_xor(runsmax[rt], 16, 64));
        mw = fmaxf(mw, __shfl_xor(mw, 32, 64));
        if (quad == 0) wsm[wv][rt * 16 + col] = mw;
    }
    __syncthreads();
    float scut[RT_N];
    #pragma unroll
    for (int rt = 0; rt < RT_N; ++rt) {
        const int row = rt * 16 + col;
        float sm = fmaxf(fmaxf(wsm[0][row], wsm[1][row]),
                         fmaxf(wsm[2][row], wsm[3][row]));
        scut[rt] = sm - SMARG;
    }

    // ================= PASS 2: capture vs fixed cut =================
    {
        short8 nb0, nb1;
        float4 pa, pb, pc, pd;
        if constexpr (BF16CB) {
            nb0 = *(const short8*)(bq0);
            nb1 = *(const short8*)(bq0 + 32);
        } else {
            pa = *(const float4*)(bp0);      pb = *(const float4*)(bp0 + 4);
            pc = *(const float4*)(bp0 + 32); pd = *(const float4*)(bp0 + 36);
        }
        #pragma unroll 1
        for (int t = 0; t < 16; ++t) {
            const int kb = (t * 4 + wv) * 16 + quad * 4;
            short8 b0, b1;
            if constexpr (BF16CB) {
                b0 = nb0; b1 = nb1;
                if (t < 15) {
                    const unsigned short* nx = bq0 + (size_t)(t + 1) * 4096;
                    nb0 = *(const short8*)(nx);
                    nb1 = *(const short8*)(nx + 32);
                }
            } else {
                float4 ca = pa, cb4 = pb, cc = pc, cd = pd;
                if (t < 15) {
                    const float* nx = bp0 + (size_t)(t + 1) * 4096;
                    pa = *(const float4*)(nx);      pb = *(const float4*)(nx + 4);
                    pc = *(const float4*)(nx + 32); pd = *(const float4*)(nx + 36);
                }
                b0[0] = (short)f2bf(ca.x);  b0[1] = (short)f2bf(ca.y);
                b0[2] = (short)f2bf(ca.z);  b0[3] = (short)f2bf(ca.w);
                b0[4] = (short)f2bf(cb4.x); b0[5] = (short)f2bf(cb4.y);
                b0[6] = (short)f2bf(cb4.z); b0[7] = (short)f2bf(cb4.w);
                b1[0] = (short)f2bf(cc.x);  b1[1] = (short)f2bf(cc.y);
                b1[2] = (short)f2bf(cc.z);  b1[3] = (short)f2bf(cc.w);
                b1[4] = (short)f2bf(cd.x);  b1[5] = (short)f2bf(cd.y);
                b1[6] = (short)f2bf(cd.z);  b1[7] = (short)f2bf(cd.w);
            }
            #pragma unroll
            for (int rt = 0; rt < RT_N; ++rt) {
                f32x4 acc = {0.f, 0.f, 0.f, 0.f};
                acc = __builtin_amdgcn_mfma_f32_16x16x32_bf16(b0, afr[rt][0], acc, 0, 0, 0);
                acc = __builtin_amdgcn_mfma_f32_16x16x32_bf16(b1, afr[rt][1], acc, 0, 0, 0);
                float m = fmaxf(fmaxf(acc[0], acc[1]), fmaxf(acc[2], acc[3]));
                if (m >= scut[rt]) {           // rare (~2-3 hits/row over whole pass)
                    const int row = rt * 16 + col;
                    #pragma unroll
                    for (int e = 0; e < 4; ++e) {
                        if (acc[e] >= scut[rt]) {
                            int p = atomicAdd(&rcnt[row], 1);
                            if (p < RCAP)
                                rlist[row * RLP + p] = (unsigned short)(kb + e);
                        }
                    }
                }
            }
        }
    }
    __syncthreads();   // rlist complete

    // ---- refine: one thread per row, np-bit-exact keys (lazy register bn) ----
    if (tid < MTILE) {
        const int r = tid;
        const int n = rcnt[r];
        int ov = (n > RCAP) ? 1 : 0;
        unsigned long long best = ~0ULL;
        if (!ov) {
            const float an = anorm[r];
            const float* xr = &xstage[r * XP];
            for (int j = 0; j < n; ++j) {
                const int k = rlist[r * RLP + j];
                unsigned long long key = np_key_full(xr, cb + (size_t)k * DIM, an, k);
                best = (key < best) ? key : best;
            }
            if (best == ~0ULL) ov = 1;   // defensive (cannot happen: k_smax captured)
        }
        if (ov) {
            int si = atomicAdd(&ovfcnt, 1);
            ovfrows[si] = r;
        } else {
            kstar[r] = (int)(best & 0xFFFULL);
            lossd[r] = (double)funmap32((unsigned int)(best >> 12));
        }
    }
    __syncthreads();

    // ---- wave-parallel exhaustive np fallback for overflowed rows (rare) ----
    const int ovfn = ovfcnt;
    for (int i = wv; i < ovfn; i += 4) {
        const int row = ovfrows[i];
        const float* xr2 = &xstage[row * XP];   // same-address LDS broadcasts
        const float an2 = anorm[row];
        unsigned long long b2 = ~0ULL;
        for (int j = 0; j < 16; ++j) {
            int k = lane * 16 + j;
            unsigned long long key = np_key_full(xr2, cb + (size_t)k * DIM, an2, k);
            b2 = (key < b2) ? key : b2;
        }
        #pragma unroll
        for (int off = 1; off < 64; off <<= 1) {
            unsigned long long o = __shfl_xor(b2, off, 64);
            b2 = (o < b2) ? o : b2;
        }
        if (lane == 0) {
            kstar[row] = (int)(b2 & 0xFFFULL);
            lossd[row] = (double)funmap32((unsigned int)(b2 >> 12));
        }
    }
    __syncthreads();

    // ---- epilogue: indices (as float), transposed quantized, loss (verified) ----
    if (tid < MTILE) out_idx[r0 + tid] = (float)kstar[tid];

    const int bb = r0 / T_LEN;
    const int t0 = r0 % T_LEN;
    const int t  = tid & 63, part = tid >> 6;
    const int kt = kstar[t];
    #pragma unroll
    for (int it = 0; it < 16; ++it) {
        int d = it * 4 + part;
        out_q[((size_t)bb * DIM + d) * T_LEN + (t0 + t)] = cb[(size_t)kt * DIM + d];
    }

    if (tid < 64) {
        double v = lossd[tid];
        #pragma unroll
        for (int off = 32; off > 0; off >>= 1) v += __shfl_down(v, off, 64);
        if (tid == 0) {
            if (use_partials) wsd[blockIdx.x] = v;
            else atomicAdd(wsd, v);
        }
    }
}

extern "C" void kernel_launch(void* const* d_in, const int* in_sizes, int n_in,
                              void* d_out, int out_size, void* d_ws, size_t ws_size,
                              hipStream_t stream) {
    const float* x  = (const float*)d_in[0];
    const float* cb = (const float*)d_in[1];
    float* out = (float*)d_out;

    const int n_x = in_sizes[0];           // 4194304
    const int n_rows = n_x / DIM;          // 65536
    const int n_blocks = n_rows / MTILE;   // 1024

    float* out_q    = out;                    // [B, D, T]
    float* out_loss = out + (size_t)n_x;      // scalar
    float* out_idx  = out + (size_t)n_x + 1;  // [B, T] as float
    double* wsd = (double*)d_ws;

    const size_t need_part = (size_t)n_blocks * sizeof(double);
    const int use_partials = (ws_size >= need_part) ? 1 : 0;
    const size_t cb_off = use_partials ? ((need_part + 15) & ~(size_t)15) : (size_t)16;
    const int use_bf = (ws_size >= cb_off + 1024 * DIM * sizeof(unsigned short)) ? 1 : 0;
    unsigned short* cbbf = (unsigned short*)((char*)d_ws + cb_off);

    if (!use_partials) vq_init_ws<<<1, 1, 0, stream>>>(wsd);
    if (use_bf) {
        vq_cvt_cb<<<64, 256, 0, stream>>>(cb, cbbf);
        vq_main<1><<<n_blocks, THREADS, 0, stream>>>(x, cb, cbbf, out_q, out_idx,
                                                     wsd, use_partials);
    } else {
        vq_main<0><<<n_blocks, THREADS, 0, stream>>>(x, cb, (const unsigned short*)cb,
                                                     out_q, out_idx, wsd, use_partials);
    }
    if (use_partials) vq_finalize_part<<<1, 1024, 0, stream>>>(wsd, out_loss, n_x);
    else vq_finalize_atomic<<<1, 1, 0, stream>>>(wsd, out_loss, n_x);
}

// Round 7
// 110.378 us; speedup vs baseline: 18.5227x; 1.1880x over previous
//
#include <hip/hip_runtime.h>

#define DIM 64
#define MTILE 64         // rows per block -> 1024 blocks
#define THREADS 256
#define T_LEN 2048
#define SMARG 1e-3f      // s-space capture margin (needs 7.95e-4: pairwise 1.53e-3/2 + bn/2)
#define RCAP 16          // per-row candidate list capacity (expected ~2-3 used)
#define RT_N 4           // row-tiles (16 rows each) per block
#define XP 68            // xstage pitch in floats (272B = 17*16B, float4-aligned rows)
#define CQP 66           // epilogue codebook-row staging pitch (float2-aligned, 2-way-free)
#define RLP 17           // rlist pitch in ushorts

typedef __attribute__((ext_vector_type(8))) short short8;
typedef __attribute__((ext_vector_type(4))) float f32x4;

// monotone order-preserving map float -> u32
__device__ __forceinline__ unsigned int fmap32(float s) {
    unsigned int b = __float_as_uint(s);
    return (b & 0x80000000u) ? ~b : (b | 0x80000000u);
}
__device__ __forceinline__ float funmap32(unsigned int m) {
    unsigned int b = (m & 0x80000000u) ? (m & 0x7fffffffu) : ~m;
    return __uint_as_float(b);
}
// fp32 -> bf16 RTNE
__device__ __forceinline__ unsigned int f2bf(float f) {
    unsigned int u = __float_as_uint(f);
    return (u + 0x7FFFu + ((u >> 16) & 1u)) >> 16;
}
// numpy pairwise-sum (n=64 scalar blocked path) combine tree over 8 partials
__device__ __forceinline__ float np_combine8(const float* r) {
    return __fadd_rn(__fadd_rn(__fadd_rn(r[0], r[1]), __fadd_rn(r[2], r[3])),
                     __fadd_rn(__fadd_rn(r[4], r[5]), __fadd_rn(r[6], r[7])));
}
// numpy n=64 squared-norm register routine (verified r2-r6). Generic pointer
// (works on LDS xstage rows); float4 accesses must be 16B-aligned.
__device__ __forceinline__ float np_norm64(const float* p) {
    const float4* c4 = (const float4*)p;
    float r8[8];
    {
        float4 a = c4[0], b = c4[1];
        r8[0] = __fmul_rn(a.x, a.x); r8[1] = __fmul_rn(a.y, a.y);
        r8[2] = __fmul_rn(a.z, a.z); r8[3] = __fmul_rn(a.w, a.w);
        r8[4] = __fmul_rn(b.x, b.x); r8[5] = __fmul_rn(b.y, b.y);
        r8[6] = __fmul_rn(b.z, b.z); r8[7] = __fmul_rn(b.w, b.w);
    }
    #pragma unroll
    for (int m = 1; m < 8; ++m) {
        float4 a = c4[2 * m], b = c4[2 * m + 1];
        r8[0] = __fadd_rn(r8[0], __fmul_rn(a.x, a.x));
        r8[1] = __fadd_rn(r8[1], __fmul_rn(a.y, a.y));
        r8[2] = __fadd_rn(r8[2], __fmul_rn(a.z, a.z));
        r8[3] = __fadd_rn(r8[3], __fmul_rn(a.w, a.w));
        r8[4] = __fadd_rn(r8[4], __fmul_rn(b.x, b.x));
        r8[5] = __fadd_rn(r8[5], __fmul_rn(b.y, b.y));
        r8[6] = __fadd_rn(r8[6], __fmul_rn(b.z, b.z));
        r8[7] = __fadd_rn(r8[7], __fmul_rn(b.w, b.w));
    }
    return np_combine8(r8);
}
// numpy-bit-exact distance key with LAZY np-exact bn (verified r5): loads the
// fp32 code row to registers once, computes bn with the identical np_norm64
// partial/order structure, then the verified serial 64-FMA dot chain.
__device__ __forceinline__ unsigned long long np_key_full(
        const float* xr, const float* cr, float an, int k) {
    float4 c4[16];
    #pragma unroll
    for (int i = 0; i < 16; ++i) c4[i] = ((const float4*)cr)[i];
    float r8[8];
    {
        float4 a = c4[0], b = c4[1];
        r8[0] = __fmul_rn(a.x, a.x); r8[1] = __fmul_rn(a.y, a.y);
        r8[2] = __fmul_rn(a.z, a.z); r8[3] = __fmul_rn(a.w, a.w);
        r8[4] = __fmul_rn(b.x, b.x); r8[5] = __fmul_rn(b.y, b.y);
        r8[6] = __fmul_rn(b.z, b.z); r8[7] = __fmul_rn(b.w, b.w);
    }
    #pragma unroll
    for (int m = 1; m < 8; ++m) {
        float4 a = c4[2 * m], b = c4[2 * m + 1];
        r8[0] = __fadd_rn(r8[0], __fmul_rn(a.x, a.x));
        r8[1] = __fadd_rn(r8[1], __fmul_rn(a.y, a.y));
        r8[2] = __fadd_rn(r8[2], __fmul_rn(a.z, a.z));
        r8[3] = __fadd_rn(r8[3], __fmul_rn(a.w, a.w));
        r8[4] = __fadd_rn(r8[4], __fmul_rn(b.x, b.x));
        r8[5] = __fadd_rn(r8[5], __fmul_rn(b.y, b.y));
        r8[6] = __fadd_rn(r8[6], __fmul_rn(b.z, b.z));
        r8[7] = __fadd_rn(r8[7], __fmul_rn(b.w, b.w));
    }
    float bn = np_combine8(r8);
    float acc = 0.0f;
    #pragma unroll
    for (int i = 0; i < 16; ++i) {
        acc = __fmaf_rn(xr[4 * i + 0], c4[i].x, acc);
        acc = __fmaf_rn(xr[4 * i + 1], c4[i].y, acc);
        acc = __fmaf_rn(xr[4 * i + 2], c4[i].z, acc);
        acc = __fmaf_rn(xr[4 * i + 3], c4[i].w, acc);
    }
    float t1 = __fadd_rn(an, bn);
    float d  = __fsub_rn(t1, __fmul_rn(2.0f, acc));
    return ((unsigned long long)fmap32(d) << 12) | (unsigned long long)k;
}

__global__ void vq_init_ws(double* ws) { ws[0] = 0.0; }

__global__ void vq_finalize_atomic(const double* __restrict__ ws,
                                   float* __restrict__ out_loss, int n_el) {
    out_loss[0] = (float)(1.25 * ws[0] / (double)n_el);
}

// reduces 1024 per-block partials (launched with 1024 threads)
__global__ void vq_finalize_part(const double* __restrict__ ws,
                                 float* __restrict__ out_loss, int n_el) {
    __shared__ double red[16];
    double v = ws[threadIdx.x];
    #pragma unroll
    for (int off = 32; off > 0; off >>= 1) v += __shfl_down(v, off, 64);
    if ((threadIdx.x & 63) == 0) red[threadIdx.x >> 6] = v;
    __syncthreads();
    if (threadIdx.x == 0) {
        double s = 0.0;
        #pragma unroll
        for (int i = 0; i < 16; ++i) s += red[i];
        out_loss[0] = (float)(1.25 * s / (double)n_el);
    }
}

// one-time fp32 -> bf16 codebook conversion + PRE-SWIZZLE into per-lane MFMA
// fragment order: swz[(tile*2 + half)*64 + lane] = 8 bf16 of code (tile*16 +
// (lane&15)), dims half*32 + (lane>>4)*8 .. +7. The scan's fragment load then
// becomes 64 lanes x 16B CONTIGUOUS (one 1KB transaction) instead of a
// 16-segment gather. Same f2bf bits as in-kernel conversion.
__global__ void vq_cvt_swz(const float* __restrict__ cb,
                           unsigned short* __restrict__ swz) {
    const int g = blockIdx.x * 256 + threadIdx.x;   // 0..8191 fragment groups
    const int lane = g & 63;
    const int half = (g >> 6) & 1;
    const int tile = g >> 7;                        // 0..63
    const int code = tile * 16 + (lane & 15);
    const int d0   = half * 32 + (lane >> 4) * 8;
    const float4* s = (const float4*)(cb + (size_t)code * DIM + d0);
    float4 v0 = s[0], v1 = s[1];
    short8 o;
    o[0] = (short)f2bf(v0.x); o[1] = (short)f2bf(v0.y);
    o[2] = (short)f2bf(v0.z); o[3] = (short)f2bf(v0.w);
    o[4] = (short)f2bf(v1.x); o[5] = (short)f2bf(v1.y);
    o[6] = (short)f2bf(v1.z); o[7] = (short)f2bf(v1.w);
    *(short8*)(swz + (size_t)g * 8) = o;
}

// Two-pass bnorm-free scan (s = bf16-dot; capture-equivalence margin proven
// r4/r5). Pass 1: coalesced swizzled loads -> MFMA -> fmax, 2-deep pipelined.
// Merge -> exact per-row smax. Pass 2: recompute s, capture vs fixed cut.
// Refine: 4 threads/row, np-bit-exact lazy-bn keys. Epilogue reads the
// selected codebook rows once into LDS (de-gathered) before the transposed
// store. Template<0> fallback (tiny workspace): fp32 gather path as r6.
template<int SWZ>
__global__ __launch_bounds__(THREADS) void vq_main(
        const float* __restrict__ x,
        const float* __restrict__ cb,
        const unsigned short* __restrict__ swz,
        float* __restrict__ out_q,
        float* __restrict__ out_idx,
        double* __restrict__ wsd,
        int use_partials)
{
    __shared__ float xstage[MTILE * XP];        // 17408 B; reused as cpq in epilogue
    __shared__ float wsm[4][MTILE];             // per-wave row smax
    __shared__ unsigned short rlist[MTILE * RLP];
    __shared__ int   rcnt[MTILE];
    __shared__ float anorm[MTILE];
    __shared__ int   kstar[MTILE];
    __shared__ double lossd[MTILE];
    __shared__ int   ovfrows[MTILE];
    __shared__ int   ovfcnt;

    const int tid  = threadIdx.x;
    const int lane = tid & 63;
    const int wv   = tid >> 6;         // wave 0..3
    const int col  = lane & 15;
    const int quad = lane >> 4;        // 0..3
    const int r0   = blockIdx.x * MTILE;

    if (tid == 0) ovfcnt = 0;
    if (tid < MTILE) rcnt[tid] = 0;

    // ---- stage x rows into LDS, coalesced (exact fp32 bits) ----
    {
        const int rr = tid >> 2, part = tid & 3;
        const float4* xs = (const float4*)(x + (size_t)(r0 + rr) * DIM + part * 16);
        float4 v0 = xs[0], v1 = xs[1], v2 = xs[2], v3 = xs[3];
        float* dst = &xstage[rr * XP + part * 16];
        *(float4*)&dst[0]  = v0;
        *(float4*)&dst[4]  = v1;
        *(float4*)&dst[8]  = v2;
        *(float4*)&dst[12] = v3;
    }
    __syncthreads();

    // ---- A_n from staged rows (np-exact) ----
    if (tid < MTILE) anorm[tid] = np_norm64(&xstage[tid * XP]);

    // ---- A (row) fragments from LDS with in-lane bf16 convert ----
    short8 afr[RT_N][2];
    #pragma unroll
    for (int mt = 0; mt < RT_N; ++mt) {
        #pragma unroll
        for (int kh = 0; kh < 2; ++kh) {
            const float* ap = &xstage[(mt * 16 + col) * XP + kh * 32 + quad * 8];
            float4 a = *(const float4*)ap;
            float4 b = *(const float4*)(ap + 4);
            short8 s;
            s[0] = (short)f2bf(a.x); s[1] = (short)f2bf(a.y);
            s[2] = (short)f2bf(a.z); s[3] = (short)f2bf(a.w);
            s[4] = (short)f2bf(b.x); s[5] = (short)f2bf(b.y);
            s[6] = (short)f2bf(b.z); s[7] = (short)f2bf(b.w);
            afr[mt][kh] = s;
        }
    }

    // per-lane bases. SWZ path: wave wv's tile t is kt=4t+wv; fragment group
    // base = kt*128 + half*64 + lane (x8 shorts). Coalesced 1KB per load.
    const unsigned short* sw  = swz + (size_t)wv * 1024 + (size_t)lane * 8;
    const float*          bp0 = cb  + (size_t)(wv * 16 + col) * DIM + quad * 8;

    // ================= PASS 1: pure max scan (2-deep pipeline) =================
    float runsmax[RT_N];
    #pragma unroll
    for (int rt = 0; rt < RT_N; ++rt) runsmax[rt] = -3.4e38f;

    if constexpr (SWZ) {
        short8 c0a = *(const short8*)(sw);
        short8 c0b = *(const short8*)(sw + 512);
        short8 c1a = *(const short8*)(sw + 4096);
        short8 c1b = *(const short8*)(sw + 4096 + 512);
        #pragma unroll 1
        for (int t = 0; t < 16; t += 2) {
            short8 n0a, n0b, n1a, n1b;
            const bool more = (t + 2 < 16);
            if (more) {
                const unsigned short* nx = sw + (size_t)(t + 2) * 4096;
                n0a = *(const short8*)(nx);
                n0b = *(const short8*)(nx + 512);
                n1a = *(const short8*)(nx + 4096);
                n1b = *(const short8*)(nx + 4096 + 512);
            }
            #pragma unroll
            for (int rt = 0; rt < RT_N; ++rt) {
                f32x4 acc = {0.f, 0.f, 0.f, 0.f};
                acc = __builtin_amdgcn_mfma_f32_16x16x32_bf16(c0a, afr[rt][0], acc, 0, 0, 0);
                acc = __builtin_amdgcn_mfma_f32_16x16x32_bf16(c0b, afr[rt][1], acc, 0, 0, 0);
                runsmax[rt] = fmaxf(runsmax[rt],
                    fmaxf(fmaxf(acc[0], acc[1]), fmaxf(acc[2], acc[3])));
            }
            #pragma unroll
            for (int rt = 0; rt < RT_N; ++rt) {
                f32x4 acc = {0.f, 0.f, 0.f, 0.f};
                acc = __builtin_amdgcn_mfma_f32_16x16x32_bf16(c1a, afr[rt][0], acc, 0, 0, 0);
                acc = __builtin_amdgcn_mfma_f32_16x16x32_bf16(c1b, afr[rt][1], acc, 0, 0, 0);
                runsmax[rt] = fmaxf(runsmax[rt],
                    fmaxf(fmaxf(acc[0], acc[1]), fmaxf(acc[2], acc[3])));
            }
            if (more) { c0a = n0a; c0b = n0b; c1a = n1a; c1b = n1b; }
        }
    } else {
        float4 pa = *(const float4*)(bp0);      float4 pb = *(const float4*)(bp0 + 4);
        float4 pc = *(const float4*)(bp0 + 32); float4 pd = *(const float4*)(bp0 + 36);
        #pragma unroll 1
        for (int t = 0; t < 16; ++t) {
            float4 ca = pa, cb4 = pb, cc = pc, cd = pd;
            if (t < 15) {
                const float* nx = bp0 + (size_t)(t + 1) * 4096;
                pa = *(const float4*)(nx);      pb = *(const float4*)(nx + 4);
                pc = *(const float4*)(nx + 32); pd = *(const float4*)(nx + 36);
            }
            short8 b0, b1;
            b0[0] = (short)f2bf(ca.x);  b0[1] = (short)f2bf(ca.y);
            b0[2] = (short)f2bf(ca.z);  b0[3] = (short)f2bf(ca.w);
            b0[4] = (short)f2bf(cb4.x); b0[5] = (short)f2bf(cb4.y);
            b0[6] = (short)f2bf(cb4.z); b0[7] = (short)f2bf(cb4.w);
            b1[0] = (short)f2bf(cc.x);  b1[1] = (short)f2bf(cc.y);
            b1[2] = (short)f2bf(cc.z);  b1[3] = (short)f2bf(cc.w);
            b1[4] = (short)f2bf(cd.x);  b1[5] = (short)f2bf(cd.y);
            b1[6] = (short)f2bf(cd.z);  b1[7] = (short)f2bf(cd.w);
            #pragma unroll
            for (int rt = 0; rt < RT_N; ++rt) {
                f32x4 acc = {0.f, 0.f, 0.f, 0.f};
                acc = __builtin_amdgcn_mfma_f32_16x16x32_bf16(b0, afr[rt][0], acc, 0, 0, 0);
                acc = __builtin_amdgcn_mfma_f32_16x16x32_bf16(b1, afr[rt][1], acc, 0, 0, 0);
                runsmax[rt] = fmaxf(runsmax[rt],
                    fmaxf(fmaxf(acc[0], acc[1]), fmaxf(acc[2], acc[3])));
            }
        }
    }

    // merge: quads (same row) then waves via LDS -> exact final smax per row
    #pragma unroll
    for (int rt = 0; rt < RT_N; ++rt) {
        float mw = fmaxf(runsmax[rt], __shfl_xor(runsmax[rt], 16, 64));
        mw = fmaxf(mw, __shfl_xor(mw, 32, 64));
        if (quad == 0) wsm[wv][rt * 16 + col] = mw;
    }
    __syncthreads();
    float scut[RT_N];
    #pragma unroll
    for (int rt = 0; rt < RT_N; ++rt) {
        const int row = rt * 16 + col;
        float sm = fmaxf(fmaxf(wsm[0][row], wsm[1][row]),
                         fmaxf(wsm[2][row], wsm[3][row]));
        scut[rt] = sm - SMARG;
    }

    // ================= PASS 2: capture vs fixed cut =================
    if constexpr (SWZ) {
        short8 c0a = *(const short8*)(sw);
        short8 c0b = *(const short8*)(sw + 512);
        short8 c1a = *(const short8*)(sw + 4096);
        short8 c1b = *(const short8*)(sw + 4096 + 512);
        #pragma unroll 1
        for (int t = 0; t < 16; t += 2) {
            short8 n0a, n0b, n1a, n1b;
            const bool more = (t + 2 < 16);
            if (more) {
                const unsigned short* nx = sw + (size_t)(t + 2) * 4096;
                n0a = *(const short8*)(nx);
                n0b = *(const short8*)(nx + 512);
                n1a = *(const short8*)(nx + 4096);
                n1b = *(const short8*)(nx + 4096 + 512);
            }
            const int kb0 = (t * 4 + wv) * 16 + quad * 4;
            const int kb1 = ((t + 1) * 4 + wv) * 16 + quad * 4;
            #pragma unroll
            for (int rt = 0; rt < RT_N; ++rt) {
                f32x4 acc = {0.f, 0.f, 0.f, 0.f};
                acc = __builtin_amdgcn_mfma_f32_16x16x32_bf16(c0a, afr[rt][0], acc, 0, 0, 0);
                acc = __builtin_amdgcn_mfma_f32_16x16x32_bf16(c0b, afr[rt][1], acc, 0, 0, 0);
                float m = fmaxf(fmaxf(acc[0], acc[1]), fmaxf(acc[2], acc[3]));
                if (m >= scut[rt]) {
                    const int row = rt * 16 + col;
                    #pragma unroll
                    for (int e = 0; e < 4; ++e) {
                        if (acc[e] >= scut[rt]) {
                            int p = atomicAdd(&rcnt[row], 1);
                            if (p < RCAP)
                                rlist[row * RLP + p] = (unsigned short)(kb0 + e);
                        }
                    }
                }
            }
            #pragma unroll
            for (int rt = 0; rt < RT_N; ++rt) {
                f32x4 acc = {0.f, 0.f, 0.f, 0.f};
                acc = __builtin_amdgcn_mfma_f32_16x16x32_bf16(c1a, afr[rt][0], acc, 0, 0, 0);
                acc = __builtin_amdgcn_mfma_f32_16x16x32_bf16(c1b, afr[rt][1], acc, 0, 0, 0);
                float m = fmaxf(fmaxf(acc[0], acc[1]), fmaxf(acc[2], acc[3]));
                if (m >= scut[rt]) {
                    const int row = rt * 16 + col;
                    #pragma unroll
                    for (int e = 0; e < 4; ++e) {
                        if (acc[e] >= scut[rt]) {
                            int p = atomicAdd(&rcnt[row], 1);
                            if (p < RCAP)
                                rlist[row * RLP + p] = (unsigned short)(kb1 + e);
                        }
                    }
                }
            }
            if (more) { c0a = n0a; c0b = n0b; c1a = n1a; c1b = n1b; }
        }
    } else {
        float4 pa = *(const float4*)(bp0);      float4 pb = *(const float4*)(bp0 + 4);
        float4 pc = *(const float4*)(bp0 + 32); float4 pd = *(const float4*)(bp0 + 36);
        #pragma unroll 1
        for (int t = 0; t < 16; ++t) {
            const int kb = (t * 4 + wv) * 16 + quad * 4;
            float4 ca = pa, cb4 = pb, cc = pc, cd = pd;
            if (t < 15) {
                const float* nx = bp0 + (size_t)(t + 1) * 4096;
                pa = *(const float4*)(nx);      pb = *(const float4*)(nx + 4);
                pc = *(const float4*)(nx + 32); pd = *(const float4*)(nx + 36);
            }
            short8 b0, b1;
            b0[0] = (short)f2bf(ca.x);  b0[1] = (short)f2bf(ca.y);
            b0[2] = (short)f2bf(ca.z);  b0[3] = (short)f2bf(ca.w);
            b0[4] = (short)f2bf(cb4.x); b0[5] = (short)f2bf(cb4.y);
            b0[6] = (short)f2bf(cb4.z); b0[7] = (short)f2bf(cb4.w);
            b1[0] = (short)f2bf(cc.x);  b1[1] = (short)f2bf(cc.y);
            b1[2] = (short)f2bf(cc.z);  b1[3] = (short)f2bf(cc.w);
            b1[4] = (short)f2bf(cd.x);  b1[5] = (short)f2bf(cd.y);
            b1[6] = (short)f2bf(cd.z);  b1[7] = (short)f2bf(cd.w);
            #pragma unroll
            for (int rt = 0; rt < RT_N; ++rt) {
                f32x4 acc = {0.f, 0.f, 0.f, 0.f};
                acc = __builtin_amdgcn_mfma_f32_16x16x32_bf16(b0, afr[rt][0], acc, 0, 0, 0);
                acc = __builtin_amdgcn_mfma_f32_16x16x32_bf16(b1, afr[rt][1], acc, 0, 0, 0);
                float m = fmaxf(fmaxf(acc[0], acc[1]), fmaxf(acc[2], acc[3]));
                if (m >= scut[rt]) {
                    const int row = rt * 16 + col;
                    #pragma unroll
                    for (int e = 0; e < 4; ++e) {
                        if (acc[e] >= scut[rt]) {
                            int p = atomicAdd(&rcnt[row], 1);
                            if (p < RCAP)
                                rlist[row * RLP + p] = (unsigned short)(kb + e);
                        }
                    }
                }
            }
        }
    }
    __syncthreads();   // rlist complete

    // ---- refine: 4 threads/row (j strided), np-bit-exact keys, shfl merge ----
    {
        const int r  = tid >> 2;      // row 0..63 (threads 4r..4r+3: same wave)
        const int j0 = tid & 3;
        const int n  = rcnt[r];
        unsigned long long best = ~0ULL;
        if (n <= RCAP) {
            const float an = anorm[r];
            const float* xr = &xstage[r * XP];
            for (int j = j0; j < n; j += 4) {
                const int k = rlist[r * RLP + j];
                unsigned long long key = np_key_full(xr, cb + (size_t)k * DIM, an, k);
                best = (key < best) ? key : best;
            }
        }
        unsigned long long o = __shfl_xor(best, 1, 64);
        best = (o < best) ? o : best;
        o = __shfl_xor(best, 2, 64);
        best = (o < best) ? o : best;
        if (j0 == 0) {
            if (n > RCAP || best == ~0ULL) {
                int si = atomicAdd(&ovfcnt, 1);
                ovfrows[si] = r;
            } else {
                kstar[r] = (int)(best & 0xFFFULL);
                lossd[r] = (double)funmap32((unsigned int)(best >> 12));
            }
        }
    }
    __syncthreads();

    // ---- wave-parallel exhaustive np fallback for overflowed rows (rare) ----
    const int ovfn = ovfcnt;
    for (int i = wv; i < ovfn; i += 4) {
        const int row = ovfrows[i];
        const float* xr2 = &xstage[row * XP];   // same-address LDS broadcasts
        const float an2 = anorm[row];
        unsigned long long b2 = ~0ULL;
        for (int j = 0; j < 16; ++j) {
            int k = lane * 16 + j;
            unsigned long long key = np_key_full(xr2, cb + (size_t)k * DIM, an2, k);
            b2 = (key < b2) ? key : b2;
        }
        #pragma unroll
        for (int off = 1; off < 64; off <<= 1) {
            unsigned long long o = __shfl_xor(b2, off, 64);
            b2 = (o < b2) ? o : b2;
        }
        if (lane == 0) {
            kstar[row] = (int)(b2 & 0xFFFULL);
            lossd[row] = (double)funmap32((unsigned int)(b2 >> 12));
        }
    }
    __syncthreads();

    // ---- epilogue: indices; stage selected cb rows into LDS (de-gathered),
    //      then transposed quantized stores; loss reduce (verified) ----
    if (tid < MTILE) out_idx[r0 + tid] = (float)kstar[tid];

    float* cpq = xstage;   // xstage dead from here; reuse with pitch CQP=66
    {
        const int r = tid >> 2, part = tid & 3;
        const int kq = kstar[r];
        const float4* cp = (const float4*)(cb + (size_t)kq * DIM + part * 16);
        float4 v0 = cp[0], v1 = cp[1], v2 = cp[2], v3 = cp[3];
        float* dst = &cpq[r * CQP + part * 16];   // 8B-aligned: float2 writes
        *(float2*)&dst[0]  = make_float2(v0.x, v0.y);
        *(float2*)&dst[2]  = make_float2(v0.z, v0.w);
        *(float2*)&dst[4]  = make_float2(v1.x, v1.y);
        *(float2*)&dst[6]  = make_float2(v1.z, v1.w);
        *(float2*)&dst[8]  = make_float2(v2.x, v2.y);
        *(float2*)&dst[10] = make_float2(v2.z, v2.w);
        *(float2*)&dst[12] = make_float2(v3.x, v3.y);
        *(float2*)&dst[14] = make_float2(v3.z, v3.w);
    }
    __syncthreads();

    const int bb = r0 / T_LEN;
    const int t0 = r0 % T_LEN;
    const int t  = tid & 63, part = tid >> 6;
    #pragma unroll
    for (int it = 0; it < 16; ++it) {
        int d = it * 4 + part;
        out_q[((size_t)bb * DIM + d) * T_LEN + (t0 + t)] = cpq[t * CQP + d];
    }

    if (tid < 64) {
        double v = lossd[tid];
        #pragma unroll
        for (int off = 32; off > 0; off >>= 1) v += __shfl_down(v, off, 64);
        if (tid == 0) {
            if (use_partials) wsd[blockIdx.x] = v;
            else atomicAdd(wsd, v);
        }
    }
}

extern "C" void kernel_launch(void* const* d_in, const int* in_sizes, int n_in,
                              void* d_out, int out_size, void* d_ws, size_t ws_size,
                              hipStream_t stream) {
    const float* x  = (const float*)d_in[0];
    const float* cb = (const float*)d_in[1];
    float* out = (float*)d_out;

    const int n_x = in_sizes[0];           // 4194304
    const int n_rows = n_x / DIM;          // 65536
    const int n_blocks = n_rows / MTILE;   // 1024

    float* out_q    = out;                    // [B, D, T]
    float* out_loss = out + (size_t)n_x;      // scalar
    float* out_idx  = out + (size_t)n_x + 1;  // [B, T] as float
    double* wsd = (double*)d_ws;

    const size_t need_part = (size_t)n_blocks * sizeof(double);
    const int use_partials = (ws_size >= need_part) ? 1 : 0;
    const size_t cb_off = use_partials ? ((need_part + 15) & ~(size_t)15) : (size_t)16;
    const int use_swz = (ws_size >= cb_off + 1024 * DIM * sizeof(unsigned short)) ? 1 : 0;
    unsigned short* swz = (unsigned short*)((char*)d_ws + cb_off);

    if (!use_partials) vq_init_ws<<<1, 1, 0, stream>>>(wsd);
    if (use_swz) {
        vq_cvt_swz<<<32, 256, 0, stream>>>(cb, swz);
        vq_main<1><<<n_blocks, THREADS, 0, stream>>>(x, cb, swz, out_q, out_idx,
                                                     wsd, use_partials);
    } else {
        vq_main<0><<<n_blocks, THREADS, 0, stream>>>(x, cb, (const unsigned short*)cb,
                                                     out_q, out_idx, wsd, use_partials);
    }
    if (use_partials) vq_finalize_part<<<1, 1024, 0, stream>>>(wsd, out_loss, n_x);
    else vq_finalize_atomic<<<1, 1, 0, stream>>>(wsd, out_loss, n_x);
}